// Round 1
// baseline (1786.554 us; speedup 1.0000x reference)
//
#include <hip/hip_runtime.h>
#include <math.h>

#define NSP 4096   // spatial = 64*64
#define CD  256    // channels
// workspace layout (floats): Q[B][N][C], K[B][C][N], V[B][N][C], Mean[B][C][N], Std[B][C][N]
// total 5 * 4*256*4096 * 4B = 83.9 MB

// ---------------------------------------------------------------- conv1x1 GEMM
// Y = W(256x256) * X(256x4096) + bias ; TOUT ? Y[n][c] : Y[c][n]
template<bool TOUT>
__global__ __launch_bounds__(256, 2) void conv_kernel(
    const float* __restrict__ W, const float* __restrict__ bias,
    const float* __restrict__ Xall, float* __restrict__ Yall)
{
    const int b = blockIdx.z;
    const float* X = Xall + (size_t)b * CD * NSP;
    float* Y = Yall + (size_t)b * CD * NSP;
    __shared__ float Ws[8][128];
    __shared__ float Xs[8][128];
    const int t = threadIdx.x;
    const int tx = t & 15, ty = t >> 4;
    const int m0 = blockIdx.y * 128, n0 = blockIdx.x * 128;
    float acc[8][8];
#pragma unroll
    for (int i = 0; i < 8; ++i)
#pragma unroll
        for (int j = 0; j < 8; ++j) acc[i][j] = 0.f;

    for (int k0 = 0; k0 < CD; k0 += 8) {
        __syncthreads();
        {   // Ws[k][m] = W[m0+m][k0+k] (transposed stage)
            int m = t >> 1, k = (t & 1) * 4;
            float4 wv = *reinterpret_cast<const float4*>(&W[(size_t)(m0 + m) * CD + k0 + k]);
            Ws[k + 0][m] = wv.x; Ws[k + 1][m] = wv.y; Ws[k + 2][m] = wv.z; Ws[k + 3][m] = wv.w;
        }
        {   // Xs[k][n] = X[k0+k][n0+n]
            int k = t >> 5, n = (t & 31) * 4;
            *reinterpret_cast<float4*>(&Xs[k][n]) =
                *reinterpret_cast<const float4*>(&X[(size_t)(k0 + k) * NSP + n0 + n]);
        }
        __syncthreads();
#pragma unroll
        for (int k = 0; k < 8; ++k) {
            float a[8], bb[8];
            float4 a0 = *reinterpret_cast<const float4*>(&Ws[k][ty * 8]);
            float4 a1 = *reinterpret_cast<const float4*>(&Ws[k][ty * 8 + 4]);
            float4 b0 = *reinterpret_cast<const float4*>(&Xs[k][tx * 4]);
            float4 b1 = *reinterpret_cast<const float4*>(&Xs[k][64 + tx * 4]);
            a[0]=a0.x; a[1]=a0.y; a[2]=a0.z; a[3]=a0.w;
            a[4]=a1.x; a[5]=a1.y; a[6]=a1.z; a[7]=a1.w;
            bb[0]=b0.x; bb[1]=b0.y; bb[2]=b0.z; bb[3]=b0.w;
            bb[4]=b1.x; bb[5]=b1.y; bb[6]=b1.z; bb[7]=b1.w;
#pragma unroll
            for (int i = 0; i < 8; ++i)
#pragma unroll
                for (int j = 0; j < 8; ++j) acc[i][j] = fmaf(a[i], bb[j], acc[i][j]);
        }
    }
    float bv[8];
#pragma unroll
    for (int i = 0; i < 8; ++i) bv[i] = bias[m0 + ty * 8 + i];
    if (TOUT) {
        // Y[n][m] : per column j, channels contiguous -> two float4
#pragma unroll
        for (int jj = 0; jj < 8; ++jj) {
            int n = n0 + ((jj < 4) ? (tx * 4 + jj) : (64 + tx * 4 + (jj - 4)));
            float4 v0, v1;
            v0.x = acc[0][jj] + bv[0]; v0.y = acc[1][jj] + bv[1];
            v0.z = acc[2][jj] + bv[2]; v0.w = acc[3][jj] + bv[3];
            v1.x = acc[4][jj] + bv[4]; v1.y = acc[5][jj] + bv[5];
            v1.z = acc[6][jj] + bv[6]; v1.w = acc[7][jj] + bv[7];
            *reinterpret_cast<float4*>(&Y[(size_t)n * CD + m0 + ty * 8]) = v0;
            *reinterpret_cast<float4*>(&Y[(size_t)n * CD + m0 + ty * 8 + 4]) = v1;
        }
    } else {
        // Y[m][n]
#pragma unroll
        for (int i = 0; i < 8; ++i) {
            int m = m0 + ty * 8 + i;
            float4 v0, v1;
            v0.x = acc[i][0] + bv[i]; v0.y = acc[i][1] + bv[i];
            v0.z = acc[i][2] + bv[i]; v0.w = acc[i][3] + bv[i];
            v1.x = acc[i][4] + bv[i]; v1.y = acc[i][5] + bv[i];
            v1.z = acc[i][6] + bv[i]; v1.w = acc[i][7] + bv[i];
            *reinterpret_cast<float4*>(&Y[(size_t)m * NSP + n0 + tx * 4]) = v0;
            *reinterpret_cast<float4*>(&Y[(size_t)m * NSP + n0 + 64 + tx * 4]) = v1;
        }
    }
}

// ---------------------------------------------------------------- flash attention (fp32 VALU)
// Per block: 32 query rows, loop over 32 K-tiles of 128 keys.
// Writes Mean[B][C][N], Std[B][C][N] (std = sqrt(relu(E[v^2]-E[v]^2))).
__global__ __launch_bounds__(256, 2) void attn_kernel(
    const float* __restrict__ Q, const float* __restrict__ Km,
    const float* __restrict__ V, float* __restrict__ Mout, float* __restrict__ Sout)
{
    __shared__ float Qt[256][32];     // Qt[d][r] = Q[q0+r][d]     32 KB
    __shared__ float KV[4096];        // Ks[32][128] or Vs[16][256] 16 KB
    __shared__ float Pt[128][32];     // Pt[k][r]                  16 KB
    __shared__ float wredA[4][8][4];
    __shared__ float wredB[4][8][4];

    const int t = threadIdx.x;
    const int b = blockIdx.y;
    const int q0 = blockIdx.x * 32;
    const int g = t & 7;          // row group: rows g*4 .. g*4+3
    const int j = t >> 3;         // 0..31   (phaseA cols j*4.., phaseC cols j*8..)
    const int r0 = g * 4;
    const int lane = t & 63, w = t >> 6;

    const float* Qb = Q  + (size_t)b * NSP * CD;
    const float* Kb = Km + (size_t)b * CD * NSP;
    const float* Vb = V  + (size_t)b * NSP * CD;

    {   // stage Q transposed
        int r = t >> 3, d0 = (t & 7) * 4;
#pragma unroll
        for (int i = 0; i < 8; ++i) {
            int d = d0 + i * 32;
            float4 qv = *reinterpret_cast<const float4*>(&Qb[(size_t)(q0 + r) * CD + d]);
            Qt[d][r] = qv.x; Qt[d + 1][r] = qv.y; Qt[d + 2][r] = qv.z; Qt[d + 3][r] = qv.w;
        }
    }
    float accM[4][8], accS[4][8];
#pragma unroll
    for (int ri = 0; ri < 4; ++ri)
#pragma unroll
        for (int cc = 0; cc < 8; ++cc) { accM[ri][cc] = 0.f; accS[ri][cc] = 0.f; }
    float m_run[4] = {-INFINITY, -INFINITY, -INFINITY, -INFINITY};
    float l_run[4] = {0.f, 0.f, 0.f, 0.f};

    for (int kt = 0; kt < 32; ++kt) {
        const int kb = kt * 128;
        float S[4][4];
#pragma unroll
        for (int ri = 0; ri < 4; ++ri)
#pragma unroll
            for (int ci = 0; ci < 4; ++ci) S[ri][ci] = 0.f;

        // ---- phase A: S[32][128] = Q * K, staged in 8 d-chunks of 32
        for (int dc = 0; dc < 8; ++dc) {
            __syncthreads();
            {
                int dd = t >> 3, kk = (t & 7) * 16;
                const float4* src = reinterpret_cast<const float4*>(
                    &Kb[(size_t)(dc * 32 + dd) * NSP + kb + kk]);
                float4* dst = reinterpret_cast<float4*>(&KV[dd * 128 + kk]);
#pragma unroll
                for (int i = 0; i < 4; ++i) dst[i] = src[i];
            }
            __syncthreads();
#pragma unroll
            for (int dd = 0; dd < 32; ++dd) {
                float4 qv = *reinterpret_cast<const float4*>(&Qt[dc * 32 + dd][r0]);
                float4 kv = *reinterpret_cast<const float4*>(&KV[dd * 128 + j * 4]);
                float qa[4] = {qv.x, qv.y, qv.z, qv.w};
                float ka[4] = {kv.x, kv.y, kv.z, kv.w};
#pragma unroll
                for (int ri = 0; ri < 4; ++ri)
#pragma unroll
                    for (int ci = 0; ci < 4; ++ci)
                        S[ri][ci] = fmaf(qa[ri], ka[ci], S[ri][ci]);
            }
        }

        // ---- phase B: online softmax
        float lmax[4];
#pragma unroll
        for (int ri = 0; ri < 4; ++ri)
            lmax[ri] = fmaxf(fmaxf(S[ri][0], S[ri][1]), fmaxf(S[ri][2], S[ri][3]));
#pragma unroll
        for (int mk = 8; mk < 64; mk <<= 1)
#pragma unroll
            for (int ri = 0; ri < 4; ++ri) lmax[ri] = fmaxf(lmax[ri], __shfl_xor(lmax[ri], mk));
        if (lane < 8) {
#pragma unroll
            for (int ri = 0; ri < 4; ++ri) wredA[w][g][ri] = lmax[ri];
        }
        __syncthreads();
        float m_new[4];
#pragma unroll
        for (int ri = 0; ri < 4; ++ri) {
            float mm = m_run[ri];
#pragma unroll
            for (int ww = 0; ww < 4; ++ww) mm = fmaxf(mm, wredA[ww][g][ri]);
            m_new[ri] = mm;
        }
        float lsum[4] = {0.f, 0.f, 0.f, 0.f};
#pragma unroll
        for (int ri = 0; ri < 4; ++ri)
#pragma unroll
            for (int ci = 0; ci < 4; ++ci) {
                float p = __expf(S[ri][ci] - m_new[ri]);
                S[ri][ci] = p;
                lsum[ri] += p;
            }
#pragma unroll
        for (int mk = 8; mk < 64; mk <<= 1)
#pragma unroll
            for (int ri = 0; ri < 4; ++ri) lsum[ri] += __shfl_xor(lsum[ri], mk);
        if (lane < 8) {
#pragma unroll
            for (int ri = 0; ri < 4; ++ri) wredB[w][g][ri] = lsum[ri];
        }
        // stage P transposed for phase C
#pragma unroll
        for (int ci = 0; ci < 4; ++ci) {
            float4 pv;
            pv.x = S[0][ci]; pv.y = S[1][ci]; pv.z = S[2][ci]; pv.w = S[3][ci];
            *reinterpret_cast<float4*>(&Pt[j * 4 + ci][r0]) = pv;
        }
        __syncthreads();
        float scale[4];
#pragma unroll
        for (int ri = 0; ri < 4; ++ri) {
            float ts = wredB[0][g][ri] + wredB[1][g][ri] + wredB[2][g][ri] + wredB[3][g][ri];
            scale[ri] = __expf(m_run[ri] - m_new[ri]);
            l_run[ri] = l_run[ri] * scale[ri] + ts;
            m_run[ri] = m_new[ri];
        }
#pragma unroll
        for (int ri = 0; ri < 4; ++ri)
#pragma unroll
            for (int cc = 0; cc < 8; ++cc) { accM[ri][cc] *= scale[ri]; accS[ri][cc] *= scale[ri]; }

        // ---- phase C: acc += P * V  and  P * V^2, V staged in 8 kk-chunks of 16
        for (int vc = 0; vc < 8; ++vc) {
            __syncthreads();
            {
                int kk = t >> 4, c0 = (t & 15) * 16;
                const float4* src = reinterpret_cast<const float4*>(
                    &Vb[(size_t)(kb + vc * 16 + kk) * CD + c0]);
                float4* dst = reinterpret_cast<float4*>(&KV[kk * 256 + c0]);
#pragma unroll
                for (int i = 0; i < 4; ++i) dst[i] = src[i];
            }
            __syncthreads();
#pragma unroll
            for (int kk = 0; kk < 16; ++kk) {
                float4 pv = *reinterpret_cast<const float4*>(&Pt[vc * 16 + kk][r0]);
                float4 va = *reinterpret_cast<const float4*>(&KV[kk * 256 + j * 8]);
                float4 vb = *reinterpret_cast<const float4*>(&KV[kk * 256 + j * 8 + 4]);
                float p[4] = {pv.x, pv.y, pv.z, pv.w};
                float v[8] = {va.x, va.y, va.z, va.w, vb.x, vb.y, vb.z, vb.w};
                float v2[8];
#pragma unroll
                for (int cc = 0; cc < 8; ++cc) v2[cc] = v[cc] * v[cc];
#pragma unroll
                for (int ri = 0; ri < 4; ++ri)
#pragma unroll
                    for (int cc = 0; cc < 8; ++cc) {
                        accM[ri][cc] = fmaf(p[ri], v[cc], accM[ri][cc]);
                        accS[ri][cc] = fmaf(p[ri], v2[cc], accS[ri][cc]);
                    }
            }
        }
    }

    // ---- finalize: mean, std ; store transposed [B][C][N]
    float inv[4];
#pragma unroll
    for (int ri = 0; ri < 4; ++ri) inv[ri] = 1.f / l_run[ri];
#pragma unroll
    for (int cc = 0; cc < 8; ++cc) {
        int c = j * 8 + cc;
        float mvals[4], svals[4];
#pragma unroll
        for (int ri = 0; ri < 4; ++ri) {
            float mm = accM[ri][cc] * inv[ri];
            float va = accS[ri][cc] * inv[ri] - mm * mm;
            mvals[ri] = mm;
            svals[ri] = sqrtf(fmaxf(va, 0.f));
        }
        float4 mv, sv;
        mv.x = mvals[0]; mv.y = mvals[1]; mv.z = mvals[2]; mv.w = mvals[3];
        sv.x = svals[0]; sv.y = svals[1]; sv.z = svals[2]; sv.w = svals[3];
        size_t off = ((size_t)b * CD + c) * NSP + q0 + r0;
        *reinterpret_cast<float4*>(&Mout[off]) = mv;
        *reinterpret_cast<float4*>(&Sout[off]) = sv;
    }
}

// ---------------------------------------------------------------- mean-variance-norm + combine
__global__ __launch_bounds__(256) void mvn_kernel(
    const float* __restrict__ content, const float* __restrict__ Mn,
    const float* __restrict__ Sd, float* __restrict__ out)
{
    __shared__ float redS[4], redSS[4];
    const int t = threadIdx.x;
    const size_t base = (size_t)blockIdx.x * NSP;   // blockIdx.x == b*256 + c
    const float4* x4 = reinterpret_cast<const float4*>(content + base);
    float s = 0.f, ss = 0.f;
    float4 xv[4];
#pragma unroll
    for (int i = 0; i < 4; ++i) {
        float4 v = x4[i * 256 + t];
        xv[i] = v;
        s  += v.x + v.y + v.z + v.w;
        ss += v.x * v.x + v.y * v.y + v.z * v.z + v.w * v.w;
    }
#pragma unroll
    for (int mk = 1; mk < 64; mk <<= 1) { s += __shfl_xor(s, mk); ss += __shfl_xor(ss, mk); }
    if ((t & 63) == 0) { redS[t >> 6] = s; redSS[t >> 6] = ss; }
    __syncthreads();
    float tot   = redS[0] + redS[1] + redS[2] + redS[3];
    float totss = redSS[0] + redSS[1] + redSS[2] + redSS[3];
    float mu  = tot * (1.f / 4096.f);
    float var = (totss - 4096.f * mu * mu) * (1.f / 4095.f);   // ddof=1
    float rstd = 1.f / sqrtf(var + 1e-5f);
    const float4* m4 = reinterpret_cast<const float4*>(Mn + base);
    const float4* s4 = reinterpret_cast<const float4*>(Sd + base);
    float4* o4 = reinterpret_cast<float4*>(out + base);
#pragma unroll
    for (int i = 0; i < 4; ++i) {
        float4 mv = m4[i * 256 + t];
        float4 sv = s4[i * 256 + t];
        float4 v  = xv[i];
        float4 o;
        o.x = sv.x * ((v.x - mu) * rstd) + mv.x;
        o.y = sv.y * ((v.y - mu) * rstd) + mv.y;
        o.z = sv.z * ((v.z - mu) * rstd) + mv.z;
        o.w = sv.w * ((v.w - mu) * rstd) + mv.w;
        o4[i * 256 + t] = o;
    }
}

extern "C" void kernel_launch(void* const* d_in, const int* in_sizes, int n_in,
                              void* d_out, int out_size, void* d_ws, size_t ws_size,
                              hipStream_t stream)
{
    const float* content     = (const float*)d_in[0];
    const float* style       = (const float*)d_in[1];
    const float* content_key = (const float*)d_in[2];
    const float* style_key   = (const float*)d_in[3];
    const float* f_w = (const float*)d_in[4];
    const float* f_b = (const float*)d_in[5];
    const float* g_w = (const float*)d_in[6];
    const float* g_b = (const float*)d_in[7];
    const float* h_w = (const float*)d_in[8];
    const float* h_b = (const float*)d_in[9];
    float* out = (float*)d_out;

    float* ws = (float*)d_ws;
    const size_t SZ = (size_t)4 * CD * NSP;   // 4,194,304 floats per tensor
    float* Q  = ws;            // [B][N][C]
    float* K  = ws + SZ;       // [B][C][N]
    float* V  = ws + 2 * SZ;   // [B][N][C]
    float* Mn = ws + 3 * SZ;   // [B][C][N]
    float* Sd = ws + 4 * SZ;   // [B][C][N]

    dim3 cgrid(32, 2, 4);
    conv_kernel<true ><<<cgrid, 256, 0, stream>>>(f_w, f_b, content_key, Q);
    conv_kernel<false><<<cgrid, 256, 0, stream>>>(g_w, g_b, style_key, K);
    conv_kernel<true ><<<cgrid, 256, 0, stream>>>(h_w, h_b, style, V);
    attn_kernel<<<dim3(128, 4), 256, 0, stream>>>(Q, K, V, Mn, Sd);
    mvn_kernel<<<dim3(1024), 256, 0, stream>>>(content, Mn, Sd, out);
}

// Round 2
// 1050.701 us; speedup vs baseline: 1.7003x; 1.7003x over previous
//
#include <hip/hip_runtime.h>
#include <math.h>

#define NSP 4096   // spatial = 64*64
#define CD  256    // channels

typedef _Float16 half8 __attribute__((ext_vector_type(8)));
typedef _Float16 half4v __attribute__((ext_vector_type(4)));
typedef float f32x4 __attribute__((ext_vector_type(4)));

// ---------------------------------------------------------------- conv1x1 GEMM
// Y = W(256x256) * X(256x4096) + bias, split into fp16 hi/lo tensors.
// MODE 1: out [N][C] (Q, K).  MODE 0: out [C][N] (V).
template<int MODE>
__global__ __launch_bounds__(256, 2) void conv_kernel(
    const float* __restrict__ W, const float* __restrict__ bias,
    const float* __restrict__ Xall, _Float16* __restrict__ Yh, _Float16* __restrict__ Yl)
{
    const int b = blockIdx.z;
    const float* X = Xall + (size_t)b * CD * NSP;
    _Float16* Yhb = Yh + (size_t)b * CD * NSP;
    _Float16* Ylb = Yl + (size_t)b * CD * NSP;
    __shared__ float Ws[8][128];
    __shared__ float Xs[8][128];
    const int t = threadIdx.x;
    const int tx = t & 15, ty = t >> 4;
    const int m0 = blockIdx.y * 128, n0 = blockIdx.x * 128;
    float acc[8][8];
#pragma unroll
    for (int i = 0; i < 8; ++i)
#pragma unroll
        for (int j = 0; j < 8; ++j) acc[i][j] = 0.f;

    for (int k0 = 0; k0 < CD; k0 += 8) {
        __syncthreads();
        {
            int m = t >> 1, k = (t & 1) * 4;
            float4 wv = *reinterpret_cast<const float4*>(&W[(size_t)(m0 + m) * CD + k0 + k]);
            Ws[k + 0][m] = wv.x; Ws[k + 1][m] = wv.y; Ws[k + 2][m] = wv.z; Ws[k + 3][m] = wv.w;
        }
        {
            int k = t >> 5, n = (t & 31) * 4;
            *reinterpret_cast<float4*>(&Xs[k][n]) =
                *reinterpret_cast<const float4*>(&X[(size_t)(k0 + k) * NSP + n0 + n]);
        }
        __syncthreads();
#pragma unroll
        for (int k = 0; k < 8; ++k) {
            float a[8], bb[8];
            float4 a0 = *reinterpret_cast<const float4*>(&Ws[k][ty * 8]);
            float4 a1 = *reinterpret_cast<const float4*>(&Ws[k][ty * 8 + 4]);
            float4 b0 = *reinterpret_cast<const float4*>(&Xs[k][tx * 4]);
            float4 b1 = *reinterpret_cast<const float4*>(&Xs[k][64 + tx * 4]);
            a[0]=a0.x; a[1]=a0.y; a[2]=a0.z; a[3]=a0.w;
            a[4]=a1.x; a[5]=a1.y; a[6]=a1.z; a[7]=a1.w;
            bb[0]=b0.x; bb[1]=b0.y; bb[2]=b0.z; bb[3]=b0.w;
            bb[4]=b1.x; bb[5]=b1.y; bb[6]=b1.z; bb[7]=b1.w;
#pragma unroll
            for (int i = 0; i < 8; ++i)
#pragma unroll
                for (int j = 0; j < 8; ++j) acc[i][j] = fmaf(a[i], bb[j], acc[i][j]);
        }
    }
    float bv[8];
#pragma unroll
    for (int i = 0; i < 8; ++i) bv[i] = bias[m0 + ty * 8 + i];

    if (MODE == 1) {
        // out [N][C] hi/lo
#pragma unroll
        for (int jj = 0; jj < 8; ++jj) {
            int n = n0 + ((jj < 4) ? (tx * 4 + jj) : (64 + tx * 4 + (jj - 4)));
            half4v h0, h1, l0, l1;
#pragma unroll
            for (int i = 0; i < 4; ++i) {
                float y0 = acc[i][jj] + bv[i];
                _Float16 hh0 = (_Float16)y0; h0[i] = hh0; l0[i] = (_Float16)(y0 - (float)hh0);
                float y1 = acc[i + 4][jj] + bv[i + 4];
                _Float16 hh1 = (_Float16)y1; h1[i] = hh1; l1[i] = (_Float16)(y1 - (float)hh1);
            }
            size_t off = (size_t)n * CD + m0 + ty * 8;
            *reinterpret_cast<half4v*>(&Yhb[off])     = h0;
            *reinterpret_cast<half4v*>(&Yhb[off + 4]) = h1;
            *reinterpret_cast<half4v*>(&Ylb[off])     = l0;
            *reinterpret_cast<half4v*>(&Ylb[off + 4]) = l1;
        }
    } else {
        // out [C][N] hi/lo
#pragma unroll
        for (int i = 0; i < 8; ++i) {
            int m = m0 + ty * 8 + i;
#pragma unroll
            for (int grp = 0; grp < 2; ++grp) {
                half4v hv, lv;
#pragma unroll
                for (int j = 0; j < 4; ++j) {
                    float y = acc[i][grp * 4 + j] + bv[i];
                    _Float16 hh = (_Float16)y; hv[j] = hh; lv[j] = (_Float16)(y - (float)hh);
                }
                size_t off = (size_t)m * NSP + n0 + grp * 64 + tx * 4;
                *reinterpret_cast<half4v*>(&Yhb[off]) = hv;
                *reinterpret_cast<half4v*>(&Ylb[off]) = lv;
            }
        }
    }
}

// ---------------------------------------------------------------- fused MFMA flash attention
// Per block: 64 q-rows, 512 threads (8 waves), loop over 32 key-tiles of 128.
// S via 3-pass hi/lo fp16 MFMA; P single fp16 (l accumulated from rounded P);
// PV transposed (D[ch][q]) with V hi/lo and W=V^2 hi/lo (W computed in staging).
// LDS (dynamic, 150272 B):
//   [0,131072)    SB staging: S-phase {Ql[64][256]@0, Kh[128][128]@32768, Kl@65536}
//                             PV-phase {Vh[256][64]@0, Vl@32768, Wh@65536, Wl@98304}
//   [131072,147456) PB: P[64][128] fp16 (256-B rows)
//   [147456,...)  redmax[4][64], redsum[4][64], mrun[64], lrun[64], scale[64]
#define SWZ(g16, row) (((g16) * 16) ^ (((row) & 7) << 4))

__global__ __launch_bounds__(512, 2) void attn_kernel(
    const _Float16* __restrict__ Qh_g, const _Float16* __restrict__ Ql_g,
    const _Float16* __restrict__ Kh_g, const _Float16* __restrict__ Kl_g,
    const _Float16* __restrict__ Vh_g, const _Float16* __restrict__ Vl_g,
    float* __restrict__ Mout, float* __restrict__ Sout)
{
    extern __shared__ char smem[];
    const int tid = threadIdx.x;
    const int lane = tid & 63;
    const int w = tid >> 6;          // 0..7
    const int g4 = lane >> 4;        // 0..3
    const int l15 = lane & 15;
    const int wq = w >> 2, wk = w & 3;

    // XCD-aware swizzle: batch = (bid&7)>>1 (2 XCDs per batch), bijective.
    const int bid = blockIdx.x;
    const int b = (bid & 7) >> 1;
    const int qb = ((bid >> 3) << 1) | (bid & 1);
    const int q0 = qb * 64;

    const size_t bNC = (size_t)b * NSP * CD;
    const _Float16* Qhb = Qh_g + bNC;
    const _Float16* Qlb = Ql_g + bNC;
    const _Float16* Khb = Kh_g + bNC;
    const _Float16* Klb = Kl_g + bNC;
    const _Float16* Vhb = Vh_g + bNC;   // [C][N]
    const _Float16* Vlb = Vl_g + bNC;

    float* redmax = (float*)(smem + 147456);   // [4][64]
    float* redsum = redmax + 256;              // [4][64]
    float* mrunS  = redsum + 256;              // [64]
    float* lrunS  = mrunS + 64;                // [64]
    float* scaleS = lrunS + 64;                // [64]

    // prologue: Qh fragments -> registers (persist across all kt)
    half8 qh[2][8];
#pragma unroll
    for (int m = 0; m < 2; ++m)
#pragma unroll
        for (int ks = 0; ks < 8; ++ks)
            qh[m][ks] = *reinterpret_cast<const half8*>(
                Qhb + (size_t)(q0 + wq * 32 + m * 16 + l15) * CD + ks * 32 + g4 * 8);

    if (w == 0) { mrunS[lane] = -3.0e38f; lrunS[lane] = 0.f; }

    f32x4 accM[2][4], accS[2][4];
#pragma unroll
    for (int m = 0; m < 2; ++m)
#pragma unroll
        for (int nf = 0; nf < 4; ++nf) {
            accM[m][nf] = (f32x4){0.f, 0.f, 0.f, 0.f};
            accS[m][nf] = (f32x4){0.f, 0.f, 0.f, 0.f};
        }

    __syncthreads();

    for (int kt = 0; kt < 32; ++kt) {
        const int kb = kt * 128;

        // ---- ph0: stage Ql (whole d) + K hi/lo d-chunk 0
#pragma unroll
        for (int j = 0; j < 4; ++j) {
            int gi = tid + j * 512;
            { int row = gi >> 5, g = gi & 31;
              half8 v = *reinterpret_cast<const half8*>(Qlb + (size_t)(q0 + row) * CD + g * 8);
              *reinterpret_cast<half8*>(smem + row * 512 + SWZ(g, row)) = v; }
            { int row = gi >> 4, g = gi & 15;
              half8 vh2 = *reinterpret_cast<const half8*>(Khb + (size_t)(kb + row) * CD + g * 8);
              half8 vl2 = *reinterpret_cast<const half8*>(Klb + (size_t)(kb + row) * CD + g * 8);
              *reinterpret_cast<half8*>(smem + 32768 + row * 256 + SWZ(g, row)) = vh2;
              *reinterpret_cast<half8*>(smem + 65536 + row * 256 + SWZ(g, row)) = vl2; }
        }
        __syncthreads();  // B1

        // ---- ph1: preload K d-chunk 1 to regs; S-MFMA d-chunk 0
        half8 r0[4], r1[4];
#pragma unroll
        for (int j = 0; j < 4; ++j) {
            int gi = tid + j * 512, row = gi >> 4, g = gi & 15;
            r0[j] = *reinterpret_cast<const half8*>(Khb + (size_t)(kb + row) * CD + 128 + g * 8);
            r1[j] = *reinterpret_cast<const half8*>(Klb + (size_t)(kb + row) * CD + 128 + g * 8);
        }
        f32x4 s[2][2];
#pragma unroll
        for (int m = 0; m < 2; ++m)
#pragma unroll
            for (int nf = 0; nf < 2; ++nf) s[m][nf] = (f32x4){0.f, 0.f, 0.f, 0.f};

#pragma unroll
        for (int ks = 0; ks < 4; ++ks) {
            half8 bh[2], bl[2], al[2];
#pragma unroll
            for (int nf = 0; nf < 2; ++nf) {
                int key = wk * 32 + nf * 16 + l15;
                bh[nf] = *reinterpret_cast<const half8*>(smem + 32768 + key * 256 + SWZ(ks * 4 + g4, key));
                bl[nf] = *reinterpret_cast<const half8*>(smem + 65536 + key * 256 + SWZ(ks * 4 + g4, key));
            }
#pragma unroll
            for (int m = 0; m < 2; ++m) {
                int row = wq * 32 + m * 16 + l15;
                al[m] = *reinterpret_cast<const half8*>(smem + row * 512 + SWZ(ks * 4 + g4, row));
            }
#pragma unroll
            for (int m = 0; m < 2; ++m)
#pragma unroll
                for (int nf = 0; nf < 2; ++nf) {
                    s[m][nf] = __builtin_amdgcn_mfma_f32_16x16x32_f16(qh[m][ks], bh[nf], s[m][nf], 0, 0, 0);
                    s[m][nf] = __builtin_amdgcn_mfma_f32_16x16x32_f16(qh[m][ks], bl[nf], s[m][nf], 0, 0, 0);
                    s[m][nf] = __builtin_amdgcn_mfma_f32_16x16x32_f16(al[m],    bh[nf], s[m][nf], 0, 0, 0);
                }
        }
        __syncthreads();  // B2

        // ---- ph2: write K d-chunk 1
#pragma unroll
        for (int j = 0; j < 4; ++j) {
            int gi = tid + j * 512, row = gi >> 4, g = gi & 15;
            *reinterpret_cast<half8*>(smem + 32768 + row * 256 + SWZ(g, row)) = r0[j];
            *reinterpret_cast<half8*>(smem + 65536 + row * 256 + SWZ(g, row)) = r1[j];
        }
        __syncthreads();  // B3

        // ---- ph3: S-MFMA d-chunk 1; row-max
#pragma unroll
        for (int ks = 0; ks < 4; ++ks) {
            half8 bh[2], bl[2], al[2];
#pragma unroll
            for (int nf = 0; nf < 2; ++nf) {
                int key = wk * 32 + nf * 16 + l15;
                bh[nf] = *reinterpret_cast<const half8*>(smem + 32768 + key * 256 + SWZ(ks * 4 + g4, key));
                bl[nf] = *reinterpret_cast<const half8*>(smem + 65536 + key * 256 + SWZ(ks * 4 + g4, key));
            }
#pragma unroll
            for (int m = 0; m < 2; ++m) {
                int row = wq * 32 + m * 16 + l15;
                al[m] = *reinterpret_cast<const half8*>(smem + row * 512 + SWZ(16 + ks * 4 + g4, row));
            }
#pragma unroll
            for (int m = 0; m < 2; ++m)
#pragma unroll
                for (int nf = 0; nf < 2; ++nf) {
                    s[m][nf] = __builtin_amdgcn_mfma_f32_16x16x32_f16(qh[m][4 + ks], bh[nf], s[m][nf], 0, 0, 0);
                    s[m][nf] = __builtin_amdgcn_mfma_f32_16x16x32_f16(qh[m][4 + ks], bl[nf], s[m][nf], 0, 0, 0);
                    s[m][nf] = __builtin_amdgcn_mfma_f32_16x16x32_f16(al[m],        bh[nf], s[m][nf], 0, 0, 0);
                }
        }
#pragma unroll
        for (int m = 0; m < 2; ++m)
#pragma unroll
            for (int e = 0; e < 4; ++e) {
                float v = fmaxf(s[m][0][e], s[m][1][e]);
                v = fmaxf(v, __shfl_xor(v, 1));
                v = fmaxf(v, __shfl_xor(v, 2));
                v = fmaxf(v, __shfl_xor(v, 4));
                v = fmaxf(v, __shfl_xor(v, 8));
                redmax[wk * 64 + wq * 32 + m * 16 + g4 * 4 + e] = v;
            }
        __syncthreads();  // B4

        // ---- ph4: wave0 computes m_new/scale; all waves preload V chunk 0
        if (w == 0) {
            float mo = mrunS[lane];
            float mx = mo;
#pragma unroll
            for (int k2 = 0; k2 < 4; ++k2) mx = fmaxf(mx, redmax[k2 * 64 + lane]);
            float sc = __expf(mo - mx);
            scaleS[lane] = sc; mrunS[lane] = mx; lrunS[lane] *= sc;
        }
#pragma unroll
        for (int j = 0; j < 4; ++j) {
            int gi = tid + j * 512, row = gi >> 3, g = gi & 7;
            r0[j] = *reinterpret_cast<const half8*>(Vhb + (size_t)row * NSP + kb + g * 8);
            r1[j] = *reinterpret_cast<const half8*>(Vlb + (size_t)row * NSP + kb + g * 8);
        }
        __syncthreads();  // B5

        // ---- ph5: p~ + P write + redsum + acc rescale; V chunk 0 ds-write (+W)
        float rs[2][4];
#pragma unroll
        for (int m = 0; m < 2; ++m) {
            int rbase = wq * 32 + m * 16 + g4 * 4;
#pragma unroll
            for (int e = 0; e < 4; ++e) {
                float mn = mrunS[rbase + e];
                float a = 0.f;
#pragma unroll
                for (int nf = 0; nf < 2; ++nf) {
                    float p = __expf(s[m][nf][e] - mn);
                    _Float16 hp = (_Float16)p;
                    int row = rbase + e, key = wk * 32 + nf * 16 + l15;
                    *reinterpret_cast<_Float16*>(smem + 131072 + row * 256 + ((key * 2) ^ ((row & 7) << 4))) = hp;
                    a += (float)hp;
                }
                rs[m][e] = a;
            }
        }
#pragma unroll
        for (int m = 0; m < 2; ++m)
#pragma unroll
            for (int e = 0; e < 4; ++e) {
                float v = rs[m][e];
                v += __shfl_xor(v, 1); v += __shfl_xor(v, 2);
                v += __shfl_xor(v, 4); v += __shfl_xor(v, 8);
                redsum[wk * 64 + wq * 32 + m * 16 + g4 * 4 + e] = v;
            }
        {
            float scq[4];
#pragma unroll
            for (int nf = 0; nf < 4; ++nf) scq[nf] = scaleS[nf * 16 + l15];
#pragma unroll
            for (int m = 0; m < 2; ++m)
#pragma unroll
                for (int nf = 0; nf < 4; ++nf) {
#pragma unroll
                    for (int e = 0; e < 4; ++e) {
                        accM[m][nf][e] *= scq[nf];
                        accS[m][nf][e] *= scq[nf];
                    }
                }
        }
#pragma unroll
        for (int j = 0; j < 4; ++j) {
            int gi = tid + j * 512, row = gi >> 3, g = gi & 7;
            half8 wh, wl;
#pragma unroll
            for (int e = 0; e < 8; ++e) {
                float v = (float)r0[j][e] + (float)r1[j][e];
                float wv = v * v;
                _Float16 hh = (_Float16)wv;
                wh[e] = hh; wl[e] = (_Float16)(wv - (float)hh);
            }
            *reinterpret_cast<half8*>(smem +         row * 128 + SWZ(g, row)) = r0[j];
            *reinterpret_cast<half8*>(smem + 32768 + row * 128 + SWZ(g, row)) = r1[j];
            *reinterpret_cast<half8*>(smem + 65536 + row * 128 + SWZ(g, row)) = wh;
            *reinterpret_cast<half8*>(smem + 98304 + row * 128 + SWZ(g, row)) = wl;
        }
        __syncthreads();  // B6

        // ---- ph6: wave0 lrun update; preload V chunk 1; PV-MFMA chunk 0
        if (w == 0) {
            lrunS[lane] += redsum[lane] + redsum[64 + lane] + redsum[128 + lane] + redsum[192 + lane];
        }
#pragma unroll
        for (int j = 0; j < 4; ++j) {
            int gi = tid + j * 512, row = gi >> 3, g = gi & 7;
            r0[j] = *reinterpret_cast<const half8*>(Vhb + (size_t)row * NSP + kb + 64 + g * 8);
            r1[j] = *reinterpret_cast<const half8*>(Vlb + (size_t)row * NSP + kb + 64 + g * 8);
        }
        {
            half8 pb[4][2];
#pragma unroll
            for (int nf = 0; nf < 4; ++nf)
#pragma unroll
                for (int k2 = 0; k2 < 2; ++k2) {
                    int q = nf * 16 + l15;
                    pb[nf][k2] = *reinterpret_cast<const half8*>(smem + 131072 + q * 256 + SWZ(k2 * 4 + g4, q));
                }
#pragma unroll
            for (int ts = 0; ts < 4; ++ts) {
                int off = ts * 32768;
#pragma unroll
                for (int m = 0; m < 2; ++m)
#pragma unroll
                    for (int k2 = 0; k2 < 2; ++k2) {
                        int ch = w * 32 + m * 16 + l15;
                        half8 a = *reinterpret_cast<const half8*>(smem + off + ch * 128 + SWZ(k2 * 4 + g4, ch));
#pragma unroll
                        for (int nf = 0; nf < 4; ++nf) {
                            if (ts < 2)
                                accM[m][nf] = __builtin_amdgcn_mfma_f32_16x16x32_f16(a, pb[nf][k2], accM[m][nf], 0, 0, 0);
                            else
                                accS[m][nf] = __builtin_amdgcn_mfma_f32_16x16x32_f16(a, pb[nf][k2], accS[m][nf], 0, 0, 0);
                        }
                    }
            }
        }
        __syncthreads();  // B7

        // ---- ph7: V chunk 1 ds-write (+W)
#pragma unroll
        for (int j = 0; j < 4; ++j) {
            int gi = tid + j * 512, row = gi >> 3, g = gi & 7;
            half8 wh, wl;
#pragma unroll
            for (int e = 0; e < 8; ++e) {
                float v = (float)r0[j][e] + (float)r1[j][e];
                float wv = v * v;
                _Float16 hh = (_Float16)wv;
                wh[e] = hh; wl[e] = (_Float16)(wv - (float)hh);
            }
            *reinterpret_cast<half8*>(smem +         row * 128 + SWZ(g, row)) = r0[j];
            *reinterpret_cast<half8*>(smem + 32768 + row * 128 + SWZ(g, row)) = r1[j];
            *reinterpret_cast<half8*>(smem + 65536 + row * 128 + SWZ(g, row)) = wh;
            *reinterpret_cast<half8*>(smem + 98304 + row * 128 + SWZ(g, row)) = wl;
        }
        __syncthreads();  // B8

        // ---- ph8: PV-MFMA chunk 1
        {
            half8 pb[4][2];
#pragma unroll
            for (int nf = 0; nf < 4; ++nf)
#pragma unroll
                for (int k2 = 0; k2 < 2; ++k2) {
                    int q = nf * 16 + l15;
                    pb[nf][k2] = *reinterpret_cast<const half8*>(smem + 131072 + q * 256 + SWZ(8 + k2 * 4 + g4, q));
                }
#pragma unroll
            for (int ts = 0; ts < 4; ++ts) {
                int off = ts * 32768;
#pragma unroll
                for (int m = 0; m < 2; ++m)
#pragma unroll
                    for (int k2 = 0; k2 < 2; ++k2) {
                        int ch = w * 32 + m * 16 + l15;
                        half8 a = *reinterpret_cast<const half8*>(smem + off + ch * 128 + SWZ(k2 * 4 + g4, ch));
#pragma unroll
                        for (int nf = 0; nf < 4; ++nf) {
                            if (ts < 2)
                                accM[m][nf] = __builtin_amdgcn_mfma_f32_16x16x32_f16(a, pb[nf][k2], accM[m][nf], 0, 0, 0);
                            else
                                accS[m][nf] = __builtin_amdgcn_mfma_f32_16x16x32_f16(a, pb[nf][k2], accS[m][nf], 0, 0, 0);
                        }
                    }
            }
        }
        __syncthreads();  // B9
    }

    // ---- epilogue: normalize, var->std, store [B][C][N]
    float linv[4];
#pragma unroll
    for (int nf = 0; nf < 4; ++nf) linv[nf] = 1.f / lrunS[nf * 16 + l15];
#pragma unroll
    for (int m = 0; m < 2; ++m)
#pragma unroll
        for (int nf = 0; nf < 4; ++nf) {
#pragma unroll
            for (int e = 0; e < 4; ++e) {
                float mean = accM[m][nf][e] * linv[nf];
                float sec  = accS[m][nf][e] * linv[nf];
                float var = sec - mean * mean;
                float sd = sqrtf(fmaxf(var, 0.f));
                int ch = w * 32 + m * 16 + g4 * 4 + e;
                int q  = q0 + nf * 16 + l15;
                size_t off = ((size_t)b * CD + ch) * NSP + q;
                Mout[off] = mean;
                Sout[off] = sd;
            }
        }
}

// ---------------------------------------------------------------- mean-variance-norm + combine
__global__ __launch_bounds__(256) void mvn_kernel(
    const float* __restrict__ content, const float* __restrict__ Mn,
    const float* __restrict__ Sd, float* __restrict__ out)
{
    __shared__ float redS[4], redSS[4];
    const int t = threadIdx.x;
    const size_t base = (size_t)blockIdx.x * NSP;
    const float4* x4 = reinterpret_cast<const float4*>(content + base);
    float s = 0.f, ss = 0.f;
    float4 xv[4];
#pragma unroll
    for (int i = 0; i < 4; ++i) {
        float4 v = x4[i * 256 + t];
        xv[i] = v;
        s  += v.x + v.y + v.z + v.w;
        ss += v.x * v.x + v.y * v.y + v.z * v.z + v.w * v.w;
    }
#pragma unroll
    for (int mk = 1; mk < 64; mk <<= 1) { s += __shfl_xor(s, mk); ss += __shfl_xor(ss, mk); }
    if ((t & 63) == 0) { redS[t >> 6] = s; redSS[t >> 6] = ss; }
    __syncthreads();
    float tot   = redS[0] + redS[1] + redS[2] + redS[3];
    float totss = redSS[0] + redSS[1] + redSS[2] + redSS[3];
    float mu  = tot * (1.f / 4096.f);
    float var = (totss - 4096.f * mu * mu) * (1.f / 4095.f);
    float rstd = 1.f / sqrtf(var + 1e-5f);
    const float4* m4 = reinterpret_cast<const float4*>(Mn + base);
    const float4* s4 = reinterpret_cast<const float4*>(Sd + base);
    float4* o4 = reinterpret_cast<float4*>(out + base);
#pragma unroll
    for (int i = 0; i < 4; ++i) {
        float4 mv = m4[i * 256 + t];
        float4 sv = s4[i * 256 + t];
        float4 v  = xv[i];
        float4 o;
        o.x = sv.x * ((v.x - mu) * rstd) + mv.x;
        o.y = sv.y * ((v.y - mu) * rstd) + mv.y;
        o.z = sv.z * ((v.z - mu) * rstd) + mv.z;
        o.w = sv.w * ((v.w - mu) * rstd) + mv.w;
        o4[i * 256 + t] = o;
    }
}

extern "C" void kernel_launch(void* const* d_in, const int* in_sizes, int n_in,
                              void* d_out, int out_size, void* d_ws, size_t ws_size,
                              hipStream_t stream)
{
    const float* content     = (const float*)d_in[0];
    const float* style       = (const float*)d_in[1];
    const float* content_key = (const float*)d_in[2];
    const float* style_key   = (const float*)d_in[3];
    const float* f_w = (const float*)d_in[4];
    const float* f_b = (const float*)d_in[5];
    const float* g_w = (const float*)d_in[6];
    const float* g_b = (const float*)d_in[7];
    const float* h_w = (const float*)d_in[8];
    const float* h_b = (const float*)d_in[9];
    float* out = (float*)d_out;

    const size_t TS = (size_t)4 * NSP * CD;      // elements per tensor
    _Float16* ws16 = (_Float16*)d_ws;
    _Float16* Qh = ws16;
    _Float16* Ql = ws16 + TS;
    _Float16* Kh = ws16 + 2 * TS;
    _Float16* Kl = ws16 + 3 * TS;
    _Float16* Vh = ws16 + 4 * TS;
    _Float16* Vl = ws16 + 5 * TS;
    float* Mn = (float*)(ws16 + 6 * TS);
    float* Sd = Mn + TS;

    dim3 cgrid(32, 2, 4);
    conv_kernel<1><<<cgrid, 256, 0, stream>>>(f_w, f_b, content_key, Qh, Ql);
    conv_kernel<1><<<cgrid, 256, 0, stream>>>(g_w, g_b, style_key, Kh, Kl);
    conv_kernel<0><<<cgrid, 256, 0, stream>>>(h_w, h_b, style, Vh, Vl);
    attn_kernel<<<dim3(256), 512, 150272, stream>>>(Qh, Ql, Kh, Kl, Vh, Vl, Mn, Sd);
    mvn_kernel<<<dim3(1024), 256, 0, stream>>>(content, Mn, Sd, out);
}

// Round 4
// 647.514 us; speedup vs baseline: 2.7591x; 1.6227x over previous
//
#include <hip/hip_runtime.h>
#include <math.h>

#define NSP 4096   // spatial = 64*64
#define CD  256    // channels

typedef _Float16 half8 __attribute__((ext_vector_type(8)));
typedef _Float16 half4v __attribute__((ext_vector_type(4)));
typedef float f32x4 __attribute__((ext_vector_type(4)));
typedef unsigned int u32;

#define VMCNT(n) asm volatile("s_waitcnt vmcnt(" #n ")" ::: "memory")
#define LGKM0    asm volatile("s_waitcnt lgkmcnt(0)" ::: "memory")

__device__ __forceinline__ void gl16(const void* g, void* l) {
    __builtin_amdgcn_global_load_lds((const __attribute__((address_space(1))) u32*)g,
                                     (__attribute__((address_space(3))) u32*)l, 16, 0, 0);
}

// ---------------------------------------------------------------- conv1x1 GEMM
// Y = W(256x256) * X(256x4096) + bias, split into fp16 hi/lo tensors.
// MODE 0 (Q): [N][C] linear.
// MODE 1 (K): tiled: tile=n>>5, halves addr = tile*8192 + key*256 + ((g*16 ^ ((key&7)<<4))>>1), g=d>>3
// MODE 2 (V): tiled: tile=n>>5, halves addr = tile*8192 + ch*32 + (((kin*2) ^ ((ch&3)<<4))>>1)
template<int MODE>
__global__ __launch_bounds__(256, 2) void conv_kernel(
    const float* __restrict__ W, const float* __restrict__ bias,
    const float* __restrict__ Xall, _Float16* __restrict__ Yh, _Float16* __restrict__ Yl)
{
    const int b = blockIdx.z;
    const float* X = Xall + (size_t)b * CD * NSP;
    _Float16* Yhb = Yh + (size_t)b * CD * NSP;
    _Float16* Ylb = Yl + (size_t)b * CD * NSP;
    __shared__ float Ws[8][128];
    __shared__ float Xs[8][128];
    const int t = threadIdx.x;
    const int tx = t & 15, ty = t >> 4;
    const int m0 = blockIdx.y * 128, n0 = blockIdx.x * 128;
    float acc[8][8];
#pragma unroll
    for (int i = 0; i < 8; ++i)
#pragma unroll
        for (int j = 0; j < 8; ++j) acc[i][j] = 0.f;

    for (int k0 = 0; k0 < CD; k0 += 8) {
        __syncthreads();
        {
            int m = t >> 1, k = (t & 1) * 4;
            float4 wv = *reinterpret_cast<const float4*>(&W[(size_t)(m0 + m) * CD + k0 + k]);
            Ws[k + 0][m] = wv.x; Ws[k + 1][m] = wv.y; Ws[k + 2][m] = wv.z; Ws[k + 3][m] = wv.w;
        }
        {
            int k = t >> 5, n = (t & 31) * 4;
            *reinterpret_cast<float4*>(&Xs[k][n]) =
                *reinterpret_cast<const float4*>(&X[(size_t)(k0 + k) * NSP + n0 + n]);
        }
        __syncthreads();
#pragma unroll
        for (int k = 0; k < 8; ++k) {
            float a[8], bb[8];
            float4 a0 = *reinterpret_cast<const float4*>(&Ws[k][ty * 8]);
            float4 a1 = *reinterpret_cast<const float4*>(&Ws[k][ty * 8 + 4]);
            float4 b0 = *reinterpret_cast<const float4*>(&Xs[k][tx * 4]);
            float4 b1 = *reinterpret_cast<const float4*>(&Xs[k][64 + tx * 4]);
            a[0]=a0.x; a[1]=a0.y; a[2]=a0.z; a[3]=a0.w;
            a[4]=a1.x; a[5]=a1.y; a[6]=a1.z; a[7]=a1.w;
            bb[0]=b0.x; bb[1]=b0.y; bb[2]=b0.z; bb[3]=b0.w;
            bb[4]=b1.x; bb[5]=b1.y; bb[6]=b1.z; bb[7]=b1.w;
#pragma unroll
            for (int i = 0; i < 8; ++i)
#pragma unroll
                for (int j = 0; j < 8; ++j) acc[i][j] = fmaf(a[i], bb[j], acc[i][j]);
        }
    }
    float bv[8];
#pragma unroll
    for (int i = 0; i < 8; ++i) bv[i] = bias[m0 + ty * 8 + i];

    if (MODE == 0) {
        // Q: [N][C] linear hi/lo
#pragma unroll
        for (int jj = 0; jj < 8; ++jj) {
            int n = n0 + ((jj < 4) ? (tx * 4 + jj) : (64 + tx * 4 + (jj - 4)));
            half4v h0, h1, l0, l1;
#pragma unroll
            for (int i = 0; i < 4; ++i) {
                float y0 = acc[i][jj] + bv[i];
                _Float16 hh0 = (_Float16)y0; h0[i] = hh0; l0[i] = (_Float16)(y0 - (float)hh0);
                float y1 = acc[i + 4][jj] + bv[i + 4];
                _Float16 hh1 = (_Float16)y1; h1[i] = hh1; l1[i] = (_Float16)(y1 - (float)hh1);
            }
            size_t off = (size_t)n * CD + m0 + ty * 8;
            *reinterpret_cast<half4v*>(&Yhb[off])     = h0;
            *reinterpret_cast<half4v*>(&Yhb[off + 4]) = h1;
            *reinterpret_cast<half4v*>(&Ylb[off])     = l0;
            *reinterpret_cast<half4v*>(&Ylb[off + 4]) = l1;
        }
    } else if (MODE == 1) {
        // K tiled-swizzled
#pragma unroll
        for (int jj = 0; jj < 8; ++jj) {
            int n = n0 + ((jj < 4) ? (tx * 4 + jj) : (64 + tx * 4 + (jj - 4)));
            int tile = n >> 5, key = n & 31;
            int g = (m0 + ty * 8) >> 3;
            size_t base = (size_t)tile * 8192 + (size_t)key * 256
                        + ((((g * 16)) ^ ((key & 7) << 4)) >> 1);
            half4v h0, h1, l0, l1;
#pragma unroll
            for (int i = 0; i < 4; ++i) {
                float y0 = acc[i][jj] + bv[i];
                _Float16 hh0 = (_Float16)y0; h0[i] = hh0; l0[i] = (_Float16)(y0 - (float)hh0);
                float y1 = acc[i + 4][jj] + bv[i + 4];
                _Float16 hh1 = (_Float16)y1; h1[i] = hh1; l1[i] = (_Float16)(y1 - (float)hh1);
            }
            *reinterpret_cast<half4v*>(&Yhb[base])     = h0;
            *reinterpret_cast<half4v*>(&Yhb[base + 4]) = h1;
            *reinterpret_cast<half4v*>(&Ylb[base])     = l0;
            *reinterpret_cast<half4v*>(&Ylb[base + 4]) = l1;
        }
    } else {
        // V tiled-swizzled
#pragma unroll
        for (int i = 0; i < 8; ++i) {
            int ch = m0 + ty * 8 + i;
#pragma unroll
            for (int grp = 0; grp < 2; ++grp) {
                int n = n0 + grp * 64 + tx * 4;
                int tile = n >> 5, kin = n & 31;
                half4v hv, lv;
#pragma unroll
                for (int j = 0; j < 4; ++j) {
                    float y = acc[i][grp * 4 + j] + bv[i];
                    _Float16 hh = (_Float16)y; hv[j] = hh; lv[j] = (_Float16)(y - (float)hh);
                }
                size_t base = (size_t)tile * 8192 + (size_t)ch * 32
                            + ((((kin * 2)) ^ ((ch & 3) << 4)) >> 1);
                *reinterpret_cast<half4v*>(&Yhb[base]) = hv;
                *reinterpret_cast<half4v*>(&Ylb[base]) = lv;
            }
        }
    }
}

// ---------------------------------------------------------------- fused MFMA flash attention
// 64 q-rows/block, 512 threads (8 waves), 128 key-tiles of 32.
// Counted-vmcnt pipeline: K dbuf (cooperative), V dbuf (wave-private), 2 raw barriers/tile.
// LDS map (bytes):
//   KB 0      : Kbuf[2] {hi 16K, lo 16K} each 32768
//   VB 65536  : Vbuf[2] {hi 16K, lo 16K} each 32768
//   PB 131072 : P[64][128B rows] fp16, XOR ((q&7)<<4)
//   RM 139264 : redmax [2 kf][64] f32
//   RS 139776 : redsum [2 tbuf][2 kf][64] f32
#define KB_OFF 0
#define VB_OFF 65536
#define PB_OFF 131072
#define RM_OFF 139264
#define RS_OFF 139776
#define SMEM_BYTES 140800

__global__ __launch_bounds__(512, 2) void attn_kernel(
    const _Float16* __restrict__ Qh_g, const _Float16* __restrict__ Ql_g,
    const _Float16* __restrict__ Kh_g, const _Float16* __restrict__ Kl_g,
    const _Float16* __restrict__ Vh_g, const _Float16* __restrict__ Vl_g,
    float* __restrict__ Mout, float* __restrict__ Sout)
{
    extern __shared__ char smem[];
    const int tid = threadIdx.x;
    const int lane = tid & 63;
    const int w = tid >> 6;          // 0..7
    const int g4 = lane >> 4;        // 0..3
    const int l15 = lane & 15;
    const int qf = w & 3;            // q-frag 0..3 (16 rows each)
    const int kf = w >> 2;           // k-frag 0..1 (16 keys each)

    // XCD-aware decode (bijective, 2 XCDs per batch)
    const int bid = blockIdx.x;
    const int b = (bid & 7) >> 1;
    const int qb = ((bid >> 3) << 1) | (bid & 1);
    const int q0 = qb * 64;

    const size_t bNC = (size_t)b * NSP * CD;
    const _Float16* Qhb = Qh_g + bNC;
    const _Float16* Qlb = Ql_g + bNC;
    const _Float16* Khb = Kh_g + bNC;   // tiled-swizzled
    const _Float16* Klb = Kl_g + bNC;
    const _Float16* Vhb = Vh_g + bNC;   // tiled-swizzled
    const _Float16* Vlb = Vl_g + bNC;

    // Q fragments (hi+lo) in registers, q-frag per wave
    const int qrow = q0 + qf * 16 + l15;
    half8 qh[8], ql[8];
#pragma unroll
    for (int ks = 0; ks < 8; ++ks) {
        qh[ks] = *reinterpret_cast<const half8*>(Qhb + (size_t)qrow * CD + ks * 32 + g4 * 8);
        ql[ks] = *reinterpret_cast<const half8*>(Qlb + (size_t)qrow * CD + ks * 32 + g4 * 8);
    }

    auto stageK = [&](int t, int buf) {
        const _Float16* sh = Khb + (size_t)t * 8192 + w * 1024 + lane * 8;
        const _Float16* sl = Klb + (size_t)t * 8192 + w * 1024 + lane * 8;
        char* d = smem + KB_OFF + buf * 32768 + w * 2048;
        gl16(sh,       d);
        gl16(sh + 512, d + 1024);
        gl16(sl,       d + 16384);
        gl16(sl + 512, d + 16384 + 1024);
    };
    auto stageV = [&](int t, int buf) {
        const _Float16* sh = Vhb + (size_t)t * 8192 + w * 1024 + lane * 8;
        const _Float16* sl = Vlb + (size_t)t * 8192 + w * 1024 + lane * 8;
        char* d = smem + VB_OFF + buf * 32768 + w * 2048;
        gl16(sh,       d);
        gl16(sh + 512, d + 1024);
        gl16(sl,       d + 16384);
        gl16(sl + 512, d + 16384 + 1024);
    };

    // prologue: 4 tile-groups in flight (K0,V0,K1,V1)
    stageK(0, 0); stageV(0, 0); stageK(1, 1); stageV(1, 1);

    f32x4 accM[2][4], accS[2][4];
#pragma unroll
    for (int m = 0; m < 2; ++m)
#pragma unroll
        for (int nf = 0; nf < 4; ++nf) {
            accM[m][nf] = (f32x4){0.f, 0.f, 0.f, 0.f};
            accS[m][nf] = (f32x4){0.f, 0.f, 0.f, 0.f};
        }
    float mrun = -3.0e38f, lrun = 0.f;

    const int key = kf * 16 + l15;
    const int ksw = (key & 7) << 4;

    for (int t = 0; t < 128; ++t) {
        const int buf = t & 1;

        // ---- B0: K(t) arrived everywhere
        if (t < 127) { VMCNT(12); } else { VMCNT(4); }
        LGKM0;
        __builtin_amdgcn_s_barrier();
        __builtin_amdgcn_sched_barrier(0);

        // lrun catch-up with redsum(t-1)
        if (t > 0) {
            const float* rs = (const float*)(smem + RS_OFF + ((t + 1) & 1) * 512);
            lrun += rs[lane] + rs[64 + lane];
        }

        // ---- S-phase: s[qf,kf] = Q*K^T (3-pass hi/lo)
        const char* krow = smem + KB_OFF + buf * 32768 + key * 512;
        f32x4 s = (f32x4){0.f, 0.f, 0.f, 0.f};
        __builtin_amdgcn_s_setprio(1);
#pragma unroll
        for (int ks = 0; ks < 8; ++ks) {
            int off = ((ks * 4 + g4) * 16) ^ ksw;
            half8 bh = *reinterpret_cast<const half8*>(krow + off);
            half8 bl = *reinterpret_cast<const half8*>(krow + 16384 + off);
            s = __builtin_amdgcn_mfma_f32_16x16x32_f16(qh[ks], bh, s, 0, 0, 0);
            s = __builtin_amdgcn_mfma_f32_16x16x32_f16(qh[ks], bl, s, 0, 0, 0);
            s = __builtin_amdgcn_mfma_f32_16x16x32_f16(ql[ks], bh, s, 0, 0, 0);
        }
        __builtin_amdgcn_s_setprio(0);

        // row-max (over 16 lanes of l15)
        f32x4 rmax = s;
#pragma unroll
        for (int mk = 1; mk <= 8; mk <<= 1)
#pragma unroll
            for (int e = 0; e < 4; ++e) rmax[e] = fmaxf(rmax[e], __shfl_xor(rmax[e], mk));
        if (l15 == 0)
            *reinterpret_cast<f32x4*>(smem + RM_OFF + kf * 256 + (qf * 16 + g4 * 4) * 4) = rmax;

        LGKM0;
        __builtin_amdgcn_s_barrier();   // B1: redmax visible; Kbuf[buf] free
        __builtin_amdgcn_sched_barrier(0);

        if (t + 2 < 128) stageK(t + 2, buf);

        // ---- softmax (per-lane q = lane, replicated across waves)
        const float* rmf = (const float*)(smem + RM_OFF);
        float rm01 = fmaxf(rmf[lane], rmf[64 + lane]);
        bool upd = rm01 > mrun + 6.f;        // defer-max THR=6
        float sc = upd ? __expf(mrun - rm01) : 1.f;
        if (upd) mrun = rm01;
        lrun *= sc;

        float psum[4];
#pragma unroll
        for (int e = 0; e < 4; ++e) {
            int q_e = qf * 16 + g4 * 4 + e;
            float m_e = __shfl(mrun, q_e);
            float p = __expf(s[e] - m_e);
            _Float16 hp = (_Float16)p;
            *reinterpret_cast<_Float16*>(smem + PB_OFF + q_e * 128 + ((key * 2) ^ ((q_e & 7) << 4))) = hp;
            psum[e] = (float)hp;
        }
#pragma unroll
        for (int mk = 1; mk <= 8; mk <<= 1)
#pragma unroll
            for (int e = 0; e < 4; ++e) psum[e] += __shfl_xor(psum[e], mk);
        if (l15 == 0) {
            f32x4 ps4 = {psum[0], psum[1], psum[2], psum[3]};
            *reinterpret_cast<f32x4*>(smem + RS_OFF + buf * 512 + kf * 256 + (qf * 16 + g4 * 4) * 4) = ps4;
        }

        // acc rescale (skipped when no max update anywhere)
        if (__ballot(sc < 1.f)) {
#pragma unroll
            for (int nf = 0; nf < 4; ++nf) {
                float scn = __shfl(sc, nf * 16 + l15);
#pragma unroll
                for (int m = 0; m < 2; ++m)
#pragma unroll
                    for (int e = 0; e < 4; ++e) { accM[m][nf][e] *= scn; accS[m][nf][e] *= scn; }
            }
        }

        // ---- B2: V(t) arrived (own) + P visible (all)
        if (t < 126) { VMCNT(12); } else if (t == 126) { VMCNT(8); } else { VMCNT(0); }
        LGKM0;
        __builtin_amdgcn_s_barrier();
        __builtin_amdgcn_sched_barrier(0);

        // ---- PV: acc += {Vh,Vl,Wh,Wl} x P
        half8 pb[4];
#pragma unroll
        for (int nf = 0; nf < 4; ++nf) {
            int q = nf * 16 + l15;
            pb[nf] = *reinterpret_cast<const half8*>(smem + PB_OFF + q * 128 + ((g4 * 16) ^ ((q & 7) << 4)));
        }
        const char* vb = smem + VB_OFF + buf * 32768;
        __builtin_amdgcn_s_setprio(1);
#pragma unroll
        for (int m = 0; m < 2; ++m) {
            int ch = w * 32 + m * 16 + l15;
            const char* vrow = vb + ch * 64;
            int voff = (g4 * 16) ^ ((ch & 3) << 4);
            half8 vh8 = *reinterpret_cast<const half8*>(vrow + voff);
            half8 vl8 = *reinterpret_cast<const half8*>(vrow + 16384 + voff);
            half8 wh8, wl8;
#pragma unroll
            for (int e = 0; e < 8; ++e) {
                float v = (float)vh8[e] + (float)vl8[e];
                float wv = v * v;
                _Float16 hh = (_Float16)wv;
                wh8[e] = hh; wl8[e] = (_Float16)(wv - (float)hh);
            }
#pragma unroll
            for (int nf = 0; nf < 4; ++nf) {
                accM[m][nf] = __builtin_amdgcn_mfma_f32_16x16x32_f16(vh8, pb[nf], accM[m][nf], 0, 0, 0);
                accM[m][nf] = __builtin_amdgcn_mfma_f32_16x16x32_f16(vl8, pb[nf], accM[m][nf], 0, 0, 0);
                accS[m][nf] = __builtin_amdgcn_mfma_f32_16x16x32_f16(wh8, pb[nf], accS[m][nf], 0, 0, 0);
                accS[m][nf] = __builtin_amdgcn_mfma_f32_16x16x32_f16(wl8, pb[nf], accS[m][nf], 0, 0, 0);
            }
        }
        __builtin_amdgcn_s_setprio(0);
        __builtin_amdgcn_sched_barrier(0);
        LGKM0;                       // my V-frag reads retired before DMA reuses buffer
        if (t + 2 < 128) stageV(t + 2, buf);
    }

    // ---- epilogue
    {
        const float* rs = (const float*)(smem + RS_OFF + 512);   // redsum(127) in buf 1
        lrun += rs[lane] + rs[64 + lane];
    }
    float inv = 1.f / lrun;
    float linv[4];
#pragma unroll
    for (int nf = 0; nf < 4; ++nf) linv[nf] = __shfl(inv, nf * 16 + l15);

#pragma unroll
    for (int m = 0; m < 2; ++m)
#pragma unroll
        for (int nf = 0; nf < 4; ++nf) {
            int qg = q0 + nf * 16 + l15;
#pragma unroll
            for (int e = 0; e < 4; ++e) {
                int ch = w * 32 + m * 16 + g4 * 4 + e;
                float mean = accM[m][nf][e] * linv[nf];
                float sec  = accS[m][nf][e] * linv[nf];
                float var = sec - mean * mean;
                float sd = sqrtf(fmaxf(var, 0.f));
                size_t off = ((size_t)b * CD + ch) * NSP + qg;
                Mout[off] = mean;
                Sout[off] = sd;
            }
        }
}

// ---------------------------------------------------------------- mean-variance-norm + combine
__global__ __launch_bounds__(256) void mvn_kernel(
    const float* __restrict__ content, const float* __restrict__ Mn,
    const float* __restrict__ Sd, float* __restrict__ out)
{
    __shared__ float redS[4], redSS[4];
    const int t = threadIdx.x;
    const size_t base = (size_t)blockIdx.x * NSP;
    const float4* x4 = reinterpret_cast<const float4*>(content + base);
    float s = 0.f, ss = 0.f;
    float4 xv[4];
#pragma unroll
    for (int i = 0; i < 4; ++i) {
        float4 v = x4[i * 256 + t];
        xv[i] = v;
        s  += v.x + v.y + v.z + v.w;
        ss += v.x * v.x + v.y * v.y + v.z * v.z + v.w * v.w;
    }
#pragma unroll
    for (int mk = 1; mk < 64; mk <<= 1) { s += __shfl_xor(s, mk); ss += __shfl_xor(ss, mk); }
    if ((t & 63) == 0) { redS[t >> 6] = s; redSS[t >> 6] = ss; }
    __syncthreads();
    float tot   = redS[0] + redS[1] + redS[2] + redS[3];
    float totss = redSS[0] + redSS[1] + redSS[2] + redSS[3];
    float mu  = tot * (1.f / 4096.f);
    float var = (totss - 4096.f * mu * mu) * (1.f / 4095.f);
    float rstd = 1.f / sqrtf(var + 1e-5f);
    const float4* m4 = reinterpret_cast<const float4*>(Mn + base);
    const float4* s4 = reinterpret_cast<const float4*>(Sd + base);
    float4* o4 = reinterpret_cast<float4*>(out + base);
#pragma unroll
    for (int i = 0; i < 4; ++i) {
        float4 mv = m4[i * 256 + t];
        float4 sv = s4[i * 256 + t];
        float4 v  = xv[i];
        float4 o;
        o.x = sv.x * ((v.x - mu) * rstd) + mv.x;
        o.y = sv.y * ((v.y - mu) * rstd) + mv.y;
        o.z = sv.z * ((v.z - mu) * rstd) + mv.z;
        o.w = sv.w * ((v.w - mu) * rstd) + mv.w;
        o4[i * 256 + t] = o;
    }
}

extern "C" void kernel_launch(void* const* d_in, const int* in_sizes, int n_in,
                              void* d_out, int out_size, void* d_ws, size_t ws_size,
                              hipStream_t stream)
{
    const float* content     = (const float*)d_in[0];
    const float* style       = (const float*)d_in[1];
    const float* content_key = (const float*)d_in[2];
    const float* style_key   = (const float*)d_in[3];
    const float* f_w = (const float*)d_in[4];
    const float* f_b = (const float*)d_in[5];
    const float* g_w = (const float*)d_in[6];
    const float* g_b = (const float*)d_in[7];
    const float* h_w = (const float*)d_in[8];
    const float* h_b = (const float*)d_in[9];
    float* out = (float*)d_out;

    const size_t TS = (size_t)4 * NSP * CD;      // elements per tensor
    _Float16* ws16 = (_Float16*)d_ws;
    _Float16* Qh = ws16;
    _Float16* Ql = ws16 + TS;
    _Float16* Kh = ws16 + 2 * TS;
    _Float16* Kl = ws16 + 3 * TS;
    _Float16* Vh = ws16 + 4 * TS;
    _Float16* Vl = ws16 + 5 * TS;
    float* Mn = (float*)(ws16 + 6 * TS);
    float* Sd = Mn + TS;

    dim3 cgrid(32, 2, 4);
    conv_kernel<0><<<cgrid, 256, 0, stream>>>(f_w, f_b, content_key, Qh, Ql);
    conv_kernel<1><<<cgrid, 256, 0, stream>>>(g_w, g_b, style_key, Kh, Kl);
    conv_kernel<2><<<cgrid, 256, 0, stream>>>(h_w, h_b, style, Vh, Vl);
    attn_kernel<<<dim3(256), 512, SMEM_BYTES, stream>>>(Qh, Ql, Kh, Kl, Vh, Vl, Mn, Sd);
    mvn_kernel<<<dim3(1024), 256, 0, stream>>>(content, Mn, Sd, out);
}

// Round 5
// 571.761 us; speedup vs baseline: 3.1247x; 1.1325x over previous
//
#include <hip/hip_runtime.h>
#include <math.h>

#define NSP 4096   // spatial = 64*64
#define CD  256    // channels
#define LOG2E 1.44269504f

typedef _Float16 half8 __attribute__((ext_vector_type(8)));
typedef _Float16 half4v __attribute__((ext_vector_type(4)));
typedef float f32x4 __attribute__((ext_vector_type(4)));
typedef unsigned int u32;

#define VMCNT(n) asm volatile("s_waitcnt vmcnt(" #n ")" ::: "memory")
#define LGKM0    asm volatile("s_waitcnt lgkmcnt(0)" ::: "memory")

__device__ __forceinline__ void gl16(const void* g, void* l) {
    __builtin_amdgcn_global_load_lds((const __attribute__((address_space(1))) u32*)g,
                                     (__attribute__((address_space(3))) u32*)l, 16, 0, 0);
}

// ---------------------------------------------------------------- conv1x1 GEMM
// Y = W(256x256) * X(256x4096) + bias, fp16 hi/lo outputs.
// MODE 0 (Q): [N][C] linear, scaled by LOG2E (softmax in exp2 units).
// MODE 1 (K): tiled: tile=n>>5, half-addr = tile*8192 + key*256 + ((g*16 ^ ((key&7)<<4))>>1)
// MODE 2 (V): combined hi|lo rows: half-addr = tile*16384 + ch*64 +
//             (((half*64 + g4*16 + pos*2) ^ ((ch&7)<<4)) >> 1)
template<int MODE>
__global__ __launch_bounds__(256, 2) void conv_kernel(
    const float* __restrict__ W, const float* __restrict__ bias,
    const float* __restrict__ Xall, _Float16* __restrict__ Yh, _Float16* __restrict__ Yl)
{
    const int b = blockIdx.z;
    const float* X = Xall + (size_t)b * CD * NSP;
    _Float16* Yhb = Yh + (size_t)b * CD * NSP * (MODE == 2 ? 2 : 1);
    _Float16* Ylb = (MODE == 2) ? nullptr : Yl + (size_t)b * CD * NSP;
    __shared__ float Ws[16][128];
    __shared__ float Xs[16][128];
    const int t = threadIdx.x;
    const int tx = t & 15, ty = t >> 4;
    const int m0 = blockIdx.y * 128, n0 = blockIdx.x * 128;
    float acc[8][8];
#pragma unroll
    for (int i = 0; i < 8; ++i)
#pragma unroll
        for (int j = 0; j < 8; ++j) acc[i][j] = 0.f;

    for (int k0 = 0; k0 < CD; k0 += 16) {
        __syncthreads();
        {   // Ws[k][m] = W[m0+m][k0+k]
            int m = t >> 1, k = (t & 1) * 8;
            float4 w0 = *reinterpret_cast<const float4*>(&W[(size_t)(m0 + m) * CD + k0 + k]);
            float4 w1 = *reinterpret_cast<const float4*>(&W[(size_t)(m0 + m) * CD + k0 + k + 4]);
            Ws[k + 0][m] = w0.x; Ws[k + 1][m] = w0.y; Ws[k + 2][m] = w0.z; Ws[k + 3][m] = w0.w;
            Ws[k + 4][m] = w1.x; Ws[k + 5][m] = w1.y; Ws[k + 6][m] = w1.z; Ws[k + 7][m] = w1.w;
        }
        {   // Xs[k][n] = X[k0+k][n0+n]
            int k = t >> 4, n = (t & 15) * 8;
            *reinterpret_cast<float4*>(&Xs[k][n]) =
                *reinterpret_cast<const float4*>(&X[(size_t)(k0 + k) * NSP + n0 + n]);
            *reinterpret_cast<float4*>(&Xs[k][n + 4]) =
                *reinterpret_cast<const float4*>(&X[(size_t)(k0 + k) * NSP + n0 + n + 4]);
        }
        __syncthreads();
#pragma unroll
        for (int k = 0; k < 16; ++k) {
            float a[8], bb[8];
            float4 a0 = *reinterpret_cast<const float4*>(&Ws[k][ty * 8]);
            float4 a1 = *reinterpret_cast<const float4*>(&Ws[k][ty * 8 + 4]);
            float4 b0 = *reinterpret_cast<const float4*>(&Xs[k][tx * 4]);
            float4 b1 = *reinterpret_cast<const float4*>(&Xs[k][64 + tx * 4]);
            a[0]=a0.x; a[1]=a0.y; a[2]=a0.z; a[3]=a0.w;
            a[4]=a1.x; a[5]=a1.y; a[6]=a1.z; a[7]=a1.w;
            bb[0]=b0.x; bb[1]=b0.y; bb[2]=b0.z; bb[3]=b0.w;
            bb[4]=b1.x; bb[5]=b1.y; bb[6]=b1.z; bb[7]=b1.w;
#pragma unroll
            for (int i = 0; i < 8; ++i)
#pragma unroll
                for (int j = 0; j < 8; ++j) acc[i][j] = fmaf(a[i], bb[j], acc[i][j]);
        }
    }
    float bv[8];
#pragma unroll
    for (int i = 0; i < 8; ++i) bv[i] = bias[m0 + ty * 8 + i];

    if (MODE == 0) {
#pragma unroll
        for (int jj = 0; jj < 8; ++jj) {
            int n = n0 + ((jj < 4) ? (tx * 4 + jj) : (64 + tx * 4 + (jj - 4)));
            half4v h0, h1, l0, l1;
#pragma unroll
            for (int i = 0; i < 4; ++i) {
                float y0 = (acc[i][jj] + bv[i]) * LOG2E;
                _Float16 hh0 = (_Float16)y0; h0[i] = hh0; l0[i] = (_Float16)(y0 - (float)hh0);
                float y1 = (acc[i + 4][jj] + bv[i + 4]) * LOG2E;
                _Float16 hh1 = (_Float16)y1; h1[i] = hh1; l1[i] = (_Float16)(y1 - (float)hh1);
            }
            size_t off = (size_t)n * CD + m0 + ty * 8;
            *reinterpret_cast<half4v*>(&Yhb[off])     = h0;
            *reinterpret_cast<half4v*>(&Yhb[off + 4]) = h1;
            *reinterpret_cast<half4v*>(&Ylb[off])     = l0;
            *reinterpret_cast<half4v*>(&Ylb[off + 4]) = l1;
        }
    } else if (MODE == 1) {
#pragma unroll
        for (int jj = 0; jj < 8; ++jj) {
            int n = n0 + ((jj < 4) ? (tx * 4 + jj) : (64 + tx * 4 + (jj - 4)));
            int tile = n >> 5, key = n & 31;
            int g = (m0 + ty * 8) >> 3;
            size_t base = (size_t)tile * 8192 + (size_t)key * 256
                        + ((((g * 16)) ^ ((key & 7) << 4)) >> 1);
            half4v h0, h1, l0, l1;
#pragma unroll
            for (int i = 0; i < 4; ++i) {
                float y0 = acc[i][jj] + bv[i];
                _Float16 hh0 = (_Float16)y0; h0[i] = hh0; l0[i] = (_Float16)(y0 - (float)hh0);
                float y1 = acc[i + 4][jj] + bv[i + 4];
                _Float16 hh1 = (_Float16)y1; h1[i] = hh1; l1[i] = (_Float16)(y1 - (float)hh1);
            }
            *reinterpret_cast<half4v*>(&Yhb[base])     = h0;
            *reinterpret_cast<half4v*>(&Yhb[base + 4]) = h1;
            *reinterpret_cast<half4v*>(&Ylb[base])     = l0;
            *reinterpret_cast<half4v*>(&Ylb[base + 4]) = l1;
        }
    } else {
        // V: [tile][ch][hi 32 halves | lo 32 halves], XOR ((ch&7)<<4) on byte addr
#pragma unroll
        for (int i = 0; i < 8; ++i) {
            int ch = m0 + ty * 8 + i;
            int sw = (ch & 7) << 4;
#pragma unroll
            for (int grp = 0; grp < 2; ++grp) {
                int n = n0 + grp * 64 + tx * 4;
                int tile = n >> 5, kin = n & 31;
                int g4 = kin >> 3, pos0 = kin & 7;       // pos0 in {0,4}
                half4v hv, lv;
#pragma unroll
                for (int j = 0; j < 4; ++j) {
                    float y = acc[i][grp * 4 + j] + bv[i];
                    _Float16 hh = (_Float16)y; hv[j] = hh; lv[j] = (_Float16)(y - (float)hh);
                }
                size_t rowb = (size_t)tile * 16384 + (size_t)ch * 64;
                int bh = (g4 * 16 + pos0 * 2) ^ sw;
                int bl = (64 + g4 * 16 + pos0 * 2) ^ sw;
                *reinterpret_cast<half4v*>(&Yhb[rowb + (bh >> 1)]) = hv;
                *reinterpret_cast<half4v*>(&Yhb[rowb + (bl >> 1)]) = lv;
            }
        }
    }
}

// ---------------------------------------------------------------- fused MFMA flash attention
// 64 q-rows/block, 512 threads (8 waves), 128 key-tiles of 32.
// B0: K(t)+V(t) drained; V frags + W-split hoisted into S segment;
// row-sum via ones-MFMA (no psum shfl / redsum LDS); B2 = P visibility only.
// LDS: KB 0 (K dbuf hi/lo 64K) | VB 65536 (Vhl dbuf 64K) | PB 131072 (P 8K) | RM 139264
#define KB_OFF 0
#define VB_OFF 65536
#define PB_OFF 131072
#define RM_OFF 139264
#define SMEM_BYTES 139776

__global__ __launch_bounds__(512, 2) void attn_kernel(
    const _Float16* __restrict__ Qh_g, const _Float16* __restrict__ Ql_g,
    const _Float16* __restrict__ Kh_g, const _Float16* __restrict__ Kl_g,
    const _Float16* __restrict__ Vhl_g,
    float* __restrict__ Mout, float* __restrict__ Sout)
{
    extern __shared__ char smem[];
    const int tid = threadIdx.x;
    const int lane = tid & 63;
    const int w = tid >> 6;
    const int g4 = lane >> 4;
    const int l15 = lane & 15;
    const int qf = w & 3;
    const int kf = w >> 2;

    const int bid = blockIdx.x;
    const int b = (bid & 7) >> 1;
    const int qb = ((bid >> 3) << 1) | (bid & 1);
    const int q0 = qb * 64;

    const size_t bNC = (size_t)b * NSP * CD;
    const _Float16* Qhb = Qh_g + bNC;
    const _Float16* Qlb = Ql_g + bNC;
    const _Float16* Khb = Kh_g + bNC;
    const _Float16* Klb = Kl_g + bNC;
    const _Float16* Vb  = Vhl_g + bNC * 2;   // 2 halves per element

    const int qrow = q0 + qf * 16 + l15;
    half8 qh[8], ql[8];
#pragma unroll
    for (int ks = 0; ks < 8; ++ks) {
        qh[ks] = *reinterpret_cast<const half8*>(Qhb + (size_t)qrow * CD + ks * 32 + g4 * 8);
        ql[ks] = *reinterpret_cast<const half8*>(Qlb + (size_t)qrow * CD + ks * 32 + g4 * 8);
    }

    auto stageK = [&](int t, int buf) {
        const _Float16* sh = Khb + (size_t)t * 8192 + w * 1024 + lane * 8;
        const _Float16* sl = Klb + (size_t)t * 8192 + w * 1024 + lane * 8;
        char* d = smem + KB_OFF + buf * 32768 + w * 2048;
        gl16(sh,       d);
        gl16(sh + 512, d + 1024);
        gl16(sl,       d + 16384);
        gl16(sl + 512, d + 16384 + 1024);
    };
    auto stageV = [&](int t, int buf) {
        const _Float16* s = Vb + (size_t)t * 16384 + w * 2048 + lane * 8;
        char* d = smem + VB_OFF + buf * 32768 + w * 4096;
        gl16(s,        d);
        gl16(s + 512,  d + 1024);
        gl16(s + 1024, d + 2048);
        gl16(s + 1536, d + 3072);
    };

    stageK(0, 0); stageV(0, 0); stageK(1, 1); stageV(1, 1);

    f32x4 accM[2][4], accS[2][4];
#pragma unroll
    for (int m = 0; m < 2; ++m)
#pragma unroll
        for (int nf = 0; nf < 4; ++nf) {
            accM[m][nf] = (f32x4){0.f, 0.f, 0.f, 0.f};
            accS[m][nf] = (f32x4){0.f, 0.f, 0.f, 0.f};
        }
    float mrun = -3.0e38f, lrun = 0.f;

    half8 ones8;
#pragma unroll
    for (int e = 0; e < 8; ++e) ones8[e] = (_Float16)1.f;

    const int key = kf * 16 + l15;
    const int ksw = (key & 7) << 4;

    for (int t = 0; t < 128; ++t) {
        const int buf = t & 1;

        // ---- B0: K(t) and V(t) arrived
        if (t < 127) { VMCNT(8); } else { VMCNT(0); }
        LGKM0;
        __builtin_amdgcn_s_barrier();
        __builtin_amdgcn_sched_barrier(0);

        // ---- V frags + W-split (VALU, overlaps S-MFMA below)
        half8 vh8A[2], vl8A[2], wh8A[2], wl8A[2];
#pragma unroll
        for (int m = 0; m < 2; ++m) {
            int ch = w * 32 + m * 16 + l15;
            const char* vrow = smem + VB_OFF + buf * 32768 + ch * 128;
            int sw = (ch & 7) << 4;
            half8 vh8 = *reinterpret_cast<const half8*>(vrow + ((g4 * 16) ^ sw));
            half8 vl8 = *reinterpret_cast<const half8*>(vrow + ((64 + g4 * 16) ^ sw));
            vh8A[m] = vh8; vl8A[m] = vl8;
            half8 wh8, wl8;
#pragma unroll
            for (int e = 0; e < 8; ++e) {
                float v = (float)vh8[e] + (float)vl8[e];
                float wv = v * v;
                _Float16 hh = (_Float16)wv;
                wh8[e] = hh; wl8[e] = (_Float16)(wv - (float)hh);
            }
            wh8A[m] = wh8; wl8A[m] = wl8;
        }

        // ---- S-phase: s[qf,kf] = Q*K^T (3-pass hi/lo), log2-units
        const char* krow = smem + KB_OFF + buf * 32768 + key * 512;
        f32x4 s = (f32x4){0.f, 0.f, 0.f, 0.f};
        __builtin_amdgcn_s_setprio(1);
#pragma unroll
        for (int ks = 0; ks < 8; ++ks) {
            int off = ((ks * 4 + g4) * 16) ^ ksw;
            half8 bh = *reinterpret_cast<const half8*>(krow + off);
            half8 bl = *reinterpret_cast<const half8*>(krow + 16384 + off);
            s = __builtin_amdgcn_mfma_f32_16x16x32_f16(qh[ks], bh, s, 0, 0, 0);
            s = __builtin_amdgcn_mfma_f32_16x16x32_f16(qh[ks], bl, s, 0, 0, 0);
            s = __builtin_amdgcn_mfma_f32_16x16x32_f16(ql[ks], bh, s, 0, 0, 0);
        }
        __builtin_amdgcn_s_setprio(0);

        // row-max over 16 lanes
        f32x4 rmax = s;
#pragma unroll
        for (int mk = 1; mk <= 8; mk <<= 1)
#pragma unroll
            for (int e = 0; e < 4; ++e) rmax[e] = fmaxf(rmax[e], __shfl_xor(rmax[e], mk));
        if (l15 == 0)
            *reinterpret_cast<f32x4*>(smem + RM_OFF + kf * 256 + (qf * 16 + g4 * 4) * 4) = rmax;

        LGKM0;
        __builtin_amdgcn_s_barrier();   // B1: redmax visible; Kbuf free
        __builtin_amdgcn_sched_barrier(0);

        if (t + 2 < 128) stageK(t + 2, buf);

        // ---- softmax (per-lane q = lane, replicated)
        const float* rmf = (const float*)(smem + RM_OFF);
        float rm01 = fmaxf(rmf[lane], rmf[64 + lane]);
        bool upd = rm01 > mrun + 8.f;        // defer-max, log2 units (P <= 2^8)
        float sc = upd ? __builtin_amdgcn_exp2f(mrun - rm01) : 1.f;
        if (upd) mrun = rm01;

#pragma unroll
        for (int e = 0; e < 4; ++e) {
            int q_e = qf * 16 + g4 * 4 + e;
            float m_e = __shfl(mrun, q_e);
            float p = __builtin_amdgcn_exp2f(s[e] - m_e);
            _Float16 hp = (_Float16)p;
            *reinterpret_cast<_Float16*>(smem + PB_OFF + q_e * 128 + ((key * 2) ^ ((q_e & 7) << 4))) = hp;
        }

        if (__ballot(sc < 1.f)) {
#pragma unroll
            for (int nf = 0; nf < 4; ++nf) {
                float scn = __shfl(sc, nf * 16 + l15);
#pragma unroll
                for (int m = 0; m < 2; ++m)
#pragma unroll
                    for (int e = 0; e < 4; ++e) { accM[m][nf][e] *= scn; accS[m][nf][e] *= scn; }
            }
        }

        // ---- B2: P visible to all waves
        LGKM0;
        __builtin_amdgcn_s_barrier();
        __builtin_amdgcn_sched_barrier(0);

        // ---- PV: rowsum (ones) + acc += {Vh,Vl,Wh,Wl} x P
        half8 pb[4];
#pragma unroll
        for (int nf = 0; nf < 4; ++nf) {
            int q = nf * 16 + l15;
            pb[nf] = *reinterpret_cast<const half8*>(smem + PB_OFF + q * 128 + ((g4 * 16) ^ ((q & 7) << 4)));
        }
        f32x4 po[4];
#pragma unroll
        for (int nf = 0; nf < 4; ++nf) po[nf] = (f32x4){0.f, 0.f, 0.f, 0.f};
        __builtin_amdgcn_s_setprio(1);
#pragma unroll
        for (int nf = 0; nf < 4; ++nf)
            po[nf] = __builtin_amdgcn_mfma_f32_16x16x32_f16(ones8, pb[nf], po[nf], 0, 0, 0);
#pragma unroll
        for (int m = 0; m < 2; ++m) {
#pragma unroll
            for (int nf = 0; nf < 4; ++nf) {
                accM[m][nf] = __builtin_amdgcn_mfma_f32_16x16x32_f16(vh8A[m], pb[nf], accM[m][nf], 0, 0, 0);
                accM[m][nf] = __builtin_amdgcn_mfma_f32_16x16x32_f16(vl8A[m], pb[nf], accM[m][nf], 0, 0, 0);
                accS[m][nf] = __builtin_amdgcn_mfma_f32_16x16x32_f16(wh8A[m], pb[nf], accS[m][nf], 0, 0, 0);
                accS[m][nf] = __builtin_amdgcn_mfma_f32_16x16x32_f16(wl8A[m], pb[nf], accS[m][nf], 0, 0, 0);
            }
        }
        __builtin_amdgcn_s_setprio(0);

        // lrun update from ones rowsum (q = lane -> nf = g4)
        float rsum = (g4 == 0) ? po[0][0] : (g4 == 1) ? po[1][0] : (g4 == 2) ? po[2][0] : po[3][0];
        lrun = lrun * sc + rsum;

        __builtin_amdgcn_sched_barrier(0);
        LGKM0;
        if (t + 2 < 128) stageV(t + 2, buf);
    }

    // ---- epilogue
    float inv = 1.f / lrun;
    float linv[4];
#pragma unroll
    for (int nf = 0; nf < 4; ++nf) linv[nf] = __shfl(inv, nf * 16 + l15);

#pragma unroll
    for (int m = 0; m < 2; ++m)
#pragma unroll
        for (int nf = 0; nf < 4; ++nf) {
            int qg = q0 + nf * 16 + l15;
#pragma unroll
            for (int e = 0; e < 4; ++e) {
                int ch = w * 32 + m * 16 + g4 * 4 + e;
                float mean = accM[m][nf][e] * linv[nf];
                float sec  = accS[m][nf][e] * linv[nf];
                float var = sec - mean * mean;
                float sd = sqrtf(fmaxf(var, 0.f));
                size_t off = ((size_t)b * CD + ch) * NSP + qg;
                Mout[off] = mean;
                Sout[off] = sd;
            }
        }
}

// ---------------------------------------------------------------- mean-variance-norm + combine
__global__ __launch_bounds__(256) void mvn_kernel(
    const float* __restrict__ content, const float* __restrict__ Mn,
    const float* __restrict__ Sd, float* __restrict__ out)
{
    __shared__ float redS[4], redSS[4];
    const int t = threadIdx.x;
    const size_t base = (size_t)blockIdx.x * NSP;
    const float4* x4 = reinterpret_cast<const float4*>(content + base);
    float s = 0.f, ss = 0.f;
    float4 xv[4];
#pragma unroll
    for (int i = 0; i < 4; ++i) {
        float4 v = x4[i * 256 + t];
        xv[i] = v;
        s  += v.x + v.y + v.z + v.w;
        ss += v.x * v.x + v.y * v.y + v.z * v.z + v.w * v.w;
    }
#pragma unroll
    for (int mk = 1; mk < 64; mk <<= 1) { s += __shfl_xor(s, mk); ss += __shfl_xor(ss, mk); }
    if ((t & 63) == 0) { redS[t >> 6] = s; redSS[t >> 6] = ss; }
    __syncthreads();
    float tot   = redS[0] + redS[1] + redS[2] + redS[3];
    float totss = redSS[0] + redSS[1] + redSS[2] + redSS[3];
    float mu  = tot * (1.f / 4096.f);
    float var = (totss - 4096.f * mu * mu) * (1.f / 4095.f);
    float rstd = 1.f / sqrtf(var + 1e-5f);
    const float4* m4 = reinterpret_cast<const float4*>(Mn + base);
    const float4* s4 = reinterpret_cast<const float4*>(Sd + base);
    float4* o4 = reinterpret_cast<float4*>(out + base);
#pragma unroll
    for (int i = 0; i < 4; ++i) {
        float4 mv = m4[i * 256 + t];
        float4 sv = s4[i * 256 + t];
        float4 v  = xv[i];
        float4 o;
        o.x = sv.x * ((v.x - mu) * rstd) + mv.x;
        o.y = sv.y * ((v.y - mu) * rstd) + mv.y;
        o.z = sv.z * ((v.z - mu) * rstd) + mv.z;
        o.w = sv.w * ((v.w - mu) * rstd) + mv.w;
        o4[i * 256 + t] = o;
    }
}

extern "C" void kernel_launch(void* const* d_in, const int* in_sizes, int n_in,
                              void* d_out, int out_size, void* d_ws, size_t ws_size,
                              hipStream_t stream)
{
    const float* content     = (const float*)d_in[0];
    const float* style       = (const float*)d_in[1];
    const float* content_key = (const float*)d_in[2];
    const float* style_key   = (const float*)d_in[3];
    const float* f_w = (const float*)d_in[4];
    const float* f_b = (const float*)d_in[5];
    const float* g_w = (const float*)d_in[6];
    const float* g_b = (const float*)d_in[7];
    const float* h_w = (const float*)d_in[8];
    const float* h_b = (const float*)d_in[9];
    float* out = (float*)d_out;

    const size_t TS = (size_t)4 * NSP * CD;      // elements per tensor
    _Float16* ws16 = (_Float16*)d_ws;
    _Float16* Qh  = ws16;
    _Float16* Ql  = ws16 + TS;
    _Float16* Kh  = ws16 + 2 * TS;
    _Float16* Kl  = ws16 + 3 * TS;
    _Float16* Vhl = ws16 + 4 * TS;               // 2*TS halves (hi|lo interleaved rows)
    float* Mn = (float*)(ws16 + 6 * TS);
    float* Sd = Mn + TS;

    dim3 cgrid(32, 2, 4);
    conv_kernel<0><<<cgrid, 256, 0, stream>>>(f_w, f_b, content_key, Qh, Ql);
    conv_kernel<1><<<cgrid, 256, 0, stream>>>(g_w, g_b, style_key, Kh, Kl);
    conv_kernel<2><<<cgrid, 256, 0, stream>>>(h_w, h_b, style, Vhl, Vhl);
    attn_kernel<<<dim3(256), 512, SMEM_BYTES, stream>>>(Qh, Ql, Kh, Kl, Vhl, Mn, Sd);
    mvn_kernel<<<dim3(1024), 256, 0, stream>>>(content, Mn, Sd, out);
}

// Round 7
// 566.020 us; speedup vs baseline: 3.1563x; 1.0101x over previous
//
#include <hip/hip_runtime.h>
#include <math.h>

#define NSP 4096   // spatial = 64*64
#define CD  256    // channels
#define LOG2E 1.44269504f

typedef _Float16 half8 __attribute__((ext_vector_type(8)));
typedef _Float16 half4v __attribute__((ext_vector_type(4)));
typedef float f32x4 __attribute__((ext_vector_type(4)));
typedef unsigned int u32;

#define VMCNT(n) asm volatile("s_waitcnt vmcnt(" #n ")" ::: "memory")
#define LGKM0    asm volatile("s_waitcnt lgkmcnt(0)" ::: "memory")

__device__ __forceinline__ void gl16(const void* g, void* l) {
    __builtin_amdgcn_global_load_lds((const __attribute__((address_space(1))) u32*)g,
                                     (__attribute__((address_space(3))) u32*)l, 16, 0, 0);
}

// ---------------------------------------------------------------- conv1x1 GEMM
// Y = W(256x256) * X(256x4096) + bias, fp16 hi/lo outputs.
// MODE 0 (Q): [N][C] linear, scaled by LOG2E (softmax in exp2 units).
// MODE 1 (K): LDS-image tiles: tile=n>>5, half-addr = tile*8192 + key*256 + ((g*16 ^ ((key&7)<<4))>>1)
// MODE 2 (V): register-fragment order [tile][w4|h2|m4][g4][l15][8]:
//             half-addr = tile*16384 + (w*8 + h*4 + m)*512 + g4*128 + (ch&15)*8 + (kin&7)
template<int MODE>
__global__ __launch_bounds__(256, 2) void conv_kernel(
    const float* __restrict__ W, const float* __restrict__ bias,
    const float* __restrict__ Xall, _Float16* __restrict__ Yh, _Float16* __restrict__ Yl)
{
    const int b = blockIdx.z;
    const float* X = Xall + (size_t)b * CD * NSP;
    _Float16* Yhb = Yh + (size_t)b * CD * NSP * (MODE == 2 ? 2 : 1);
    _Float16* Ylb = (MODE == 2) ? nullptr : Yl + (size_t)b * CD * NSP;
    __shared__ float Ws[16][128];
    __shared__ float Xs[16][128];
    const int t = threadIdx.x;
    const int tx = t & 15, ty = t >> 4;
    const int m0 = blockIdx.y * 128, n0 = blockIdx.x * 128;
    float acc[8][8];
#pragma unroll
    for (int i = 0; i < 8; ++i)
#pragma unroll
        for (int j = 0; j < 8; ++j) acc[i][j] = 0.f;

    for (int k0 = 0; k0 < CD; k0 += 16) {
        __syncthreads();
        {
            int m = t >> 1, k = (t & 1) * 8;
            float4 w0 = *reinterpret_cast<const float4*>(&W[(size_t)(m0 + m) * CD + k0 + k]);
            float4 w1 = *reinterpret_cast<const float4*>(&W[(size_t)(m0 + m) * CD + k0 + k + 4]);
            Ws[k + 0][m] = w0.x; Ws[k + 1][m] = w0.y; Ws[k + 2][m] = w0.z; Ws[k + 3][m] = w0.w;
            Ws[k + 4][m] = w1.x; Ws[k + 5][m] = w1.y; Ws[k + 6][m] = w1.z; Ws[k + 7][m] = w1.w;
        }
        {
            int k = t >> 4, n = (t & 15) * 8;
            *reinterpret_cast<float4*>(&Xs[k][n]) =
                *reinterpret_cast<const float4*>(&X[(size_t)(k0 + k) * NSP + n0 + n]);
            *reinterpret_cast<float4*>(&Xs[k][n + 4]) =
                *reinterpret_cast<const float4*>(&X[(size_t)(k0 + k) * NSP + n0 + n + 4]);
        }
        __syncthreads();
#pragma unroll
        for (int k = 0; k < 16; ++k) {
            float a[8], bb[8];
            float4 a0 = *reinterpret_cast<const float4*>(&Ws[k][ty * 8]);
            float4 a1 = *reinterpret_cast<const float4*>(&Ws[k][ty * 8 + 4]);
            float4 b0 = *reinterpret_cast<const float4*>(&Xs[k][tx * 4]);
            float4 b1 = *reinterpret_cast<const float4*>(&Xs[k][64 + tx * 4]);
            a[0]=a0.x; a[1]=a0.y; a[2]=a0.z; a[3]=a0.w;
            a[4]=a1.x; a[5]=a1.y; a[6]=a1.z; a[7]=a1.w;
            bb[0]=b0.x; bb[1]=b0.y; bb[2]=b0.z; bb[3]=b0.w;
            bb[4]=b1.x; bb[5]=b1.y; bb[6]=b1.z; bb[7]=b1.w;
#pragma unroll
            for (int i = 0; i < 8; ++i)
#pragma unroll
                for (int j = 0; j < 8; ++j) acc[i][j] = fmaf(a[i], bb[j], acc[i][j]);
        }
    }
    float bv[8];
#pragma unroll
    for (int i = 0; i < 8; ++i) bv[i] = bias[m0 + ty * 8 + i];

    if (MODE == 0) {
#pragma unroll
        for (int jj = 0; jj < 8; ++jj) {
            int n = n0 + ((jj < 4) ? (tx * 4 + jj) : (64 + tx * 4 + (jj - 4)));
            half4v h0, h1, l0, l1;
#pragma unroll
            for (int i = 0; i < 4; ++i) {
                float y0 = (acc[i][jj] + bv[i]) * LOG2E;
                _Float16 hh0 = (_Float16)y0; h0[i] = hh0; l0[i] = (_Float16)(y0 - (float)hh0);
                float y1 = (acc[i + 4][jj] + bv[i + 4]) * LOG2E;
                _Float16 hh1 = (_Float16)y1; h1[i] = hh1; l1[i] = (_Float16)(y1 - (float)hh1);
            }
            size_t off = (size_t)n * CD + m0 + ty * 8;
            *reinterpret_cast<half4v*>(&Yhb[off])     = h0;
            *reinterpret_cast<half4v*>(&Yhb[off + 4]) = h1;
            *reinterpret_cast<half4v*>(&Ylb[off])     = l0;
            *reinterpret_cast<half4v*>(&Ylb[off + 4]) = l1;
        }
    } else if (MODE == 1) {
#pragma unroll
        for (int jj = 0; jj < 8; ++jj) {
            int n = n0 + ((jj < 4) ? (tx * 4 + jj) : (64 + tx * 4 + (jj - 4)));
            int tile = n >> 5, key = n & 31;
            int g = (m0 + ty * 8) >> 3;
            size_t base = (size_t)tile * 8192 + (size_t)key * 256
                        + ((((g * 16)) ^ ((key & 7) << 4)) >> 1);
            half4v h0, h1, l0, l1;
#pragma unroll
            for (int i = 0; i < 4; ++i) {
                float y0 = acc[i][jj] + bv[i];
                _Float16 hh0 = (_Float16)y0; h0[i] = hh0; l0[i] = (_Float16)(y0 - (float)hh0);
                float y1 = acc[i + 4][jj] + bv[i + 4];
                _Float16 hh1 = (_Float16)y1; h1[i] = hh1; l1[i] = (_Float16)(y1 - (float)hh1);
            }
            *reinterpret_cast<half4v*>(&Yhb[base])     = h0;
            *reinterpret_cast<half4v*>(&Yhb[base + 4]) = h1;
            *reinterpret_cast<half4v*>(&Ylb[base])     = l0;
            *reinterpret_cast<half4v*>(&Ylb[base + 4]) = l1;
        }
    } else {
        // V register-fragment layout (no swizzle needed; consumed by plain loads)
#pragma unroll
        for (int i = 0; i < 8; ++i) {
            int ch = m0 + ty * 8 + i;
            int wv_ = ch >> 6, mv = (ch >> 4) & 3, lv = ch & 15;
            size_t chbase = (size_t)(wv_ * 8 + mv) * 512 + lv * 8;   // h=0; +2048 for h=1
#pragma unroll
            for (int grp = 0; grp < 2; ++grp) {
                int n = n0 + grp * 64 + tx * 4;
                int tile = n >> 5, kin = n & 31;
                int g4v = kin >> 3, pos0 = kin & 7;
                half4v hv, lv4;
#pragma unroll
                for (int j = 0; j < 4; ++j) {
                    float y = acc[i][grp * 4 + j] + bv[i];
                    _Float16 hh = (_Float16)y; hv[j] = hh; lv4[j] = (_Float16)(y - (float)hh);
                }
                size_t tb = (size_t)tile * 16384 + chbase + (size_t)g4v * 128 + pos0;
                *reinterpret_cast<half4v*>(&Yhb[tb])        = hv;
                *reinterpret_cast<half4v*>(&Yhb[tb + 2048]) = lv4;
            }
        }
    }
}

// ---------------------------------------------------------------- fused MFMA flash attention
// 32 q-rows/block, 256 threads (4 waves), 128 key-tiles of 32, 512 blocks (2/CU).
// Swapped QK^T (A=K, B=Q): lane-local softmax rows. V direct global->reg (wave-private).
// LDS: KB 0 (K dbuf hi/lo 64K) | PB 65536 (P[32][128B] 4K) | RM 69632 (2x32 f32)
#define KB_OFF 0
#define PB_OFF 65536
#define RM_OFF 69632
#define SMEM_BYTES 69888

__global__ __launch_bounds__(256, 2) void attn_kernel(
    const _Float16* __restrict__ Qh_g, const _Float16* __restrict__ Ql_g,
    const _Float16* __restrict__ Kh_g, const _Float16* __restrict__ Kl_g,
    const _Float16* __restrict__ Vhl_g,
    float* __restrict__ Mout, float* __restrict__ Sout)
{
    extern __shared__ char smem[];
    const int tid = threadIdx.x;
    const int lane = tid & 63;
    const int w = tid >> 6;          // 0..3
    const int g4 = lane >> 4;        // 0..3
    const int l15 = lane & 15;
    const int kf = w & 1;            // key-frag (16 keys)
    const int qf = w >> 1;           // q-frag (16 q)

    // XCD-aware decode: 512 blocks, bid&7 = XCD, 2 XCDs per batch, bijective.
    const int bid = blockIdx.x;
    const int b = (bid & 7) >> 1;
    const int qb = ((bid >> 3) << 1) | (bid & 1);   // 0..127
    const int q0 = qb * 32;

    const size_t bNC = (size_t)b * NSP * CD;
    const _Float16* Qhb = Qh_g + bNC;
    const _Float16* Qlb = Ql_g + bNC;
    const _Float16* Khb = Kh_g + bNC;
    const _Float16* Klb = Kl_g + bNC;
    const _Float16* Vb  = Vhl_g + bNC * 2;

    // Q fragments (B-operand) in registers
    const int qrow = q0 + qf * 16 + l15;
    half8 qh[8], ql[8];
#pragma unroll
    for (int ks = 0; ks < 8; ++ks) {
        qh[ks] = *reinterpret_cast<const half8*>(Qhb + (size_t)qrow * CD + ks * 32 + g4 * 8);
        ql[ks] = *reinterpret_cast<const half8*>(Qlb + (size_t)qrow * CD + ks * 32 + g4 * 8);
    }

    auto stageK = [&](int t, int buf) {
        const _Float16* sh = Khb + (size_t)t * 8192 + tid * 8;
        const _Float16* sl = Klb + (size_t)t * 8192 + tid * 8;
        char* d = smem + KB_OFF + buf * 32768 + tid * 16;
#pragma unroll
        for (int j = 0; j < 4; ++j) {
            gl16(sh + j * 2048, d + j * 4096);
            gl16(sl + j * 2048, d + 16384 + j * 4096);
        }
    };

    stageK(0, 0); stageK(1, 1);

    f32x4 accM[4][2], accS[4][2];
#pragma unroll
    for (int m = 0; m < 4; ++m)
#pragma unroll
        for (int nf = 0; nf < 2; ++nf) {
            accM[m][nf] = (f32x4){0.f, 0.f, 0.f, 0.f};
            accS[m][nf] = (f32x4){0.f, 0.f, 0.f, 0.f};
        }
    float mrun = -3.0e38f, lrun = 0.f;

    half8 ones8;
#pragma unroll
    for (int e = 0; e < 8; ++e) ones8[e] = (_Float16)1.f;

    const int key = kf * 16 + l15;
    const int ksw = (key & 7) << 4;
    const int qloc = qf * 16 + l15;                    // this wave's q for S/P
    const int qsw = (qloc & 7) << 4;
    const size_t vlane = (size_t)g4 * 128 + (size_t)l15 * 8;

    half8 vh[4], vl[4];

    for (int t = 0; t < 128; ++t) {
        const int buf = t & 1;

        // ---- B0: K(t) arrived
        if (t <= 126) { VMCNT(8); } else { VMCNT(0); }
        LGKM0;
        __builtin_amdgcn_s_barrier();
        __builtin_amdgcn_sched_barrier(0);

        // issue V(t) loads (wave-private, register destination)
        {
            const _Float16* Vt = Vb + (size_t)t * 16384;
#pragma unroll
            for (int m = 0; m < 4; ++m) {
                vh[m] = *reinterpret_cast<const half8*>(Vt + (size_t)(w * 8 + m) * 512 + vlane);
                vl[m] = *reinterpret_cast<const half8*>(Vt + (size_t)(w * 8 + 4 + m) * 512 + vlane);
            }
        }

        // ---- S-phase: s = K x Q (3-pass hi/lo); lane: q=qloc, keys g4*4+e
        const char* krow = smem + KB_OFF + buf * 32768 + key * 512;
        f32x4 s = (f32x4){0.f, 0.f, 0.f, 0.f};
        __builtin_amdgcn_s_setprio(1);
#pragma unroll
        for (int ks = 0; ks < 8; ++ks) {
            int off = ((ks * 4 + g4) * 16) ^ ksw;
            half8 bh = *reinterpret_cast<const half8*>(krow + off);
            half8 bl = *reinterpret_cast<const half8*>(krow + 16384 + off);
            s = __builtin_amdgcn_mfma_f32_16x16x32_f16(bh, qh[ks], s, 0, 0, 0);
            s = __builtin_amdgcn_mfma_f32_16x16x32_f16(bh, ql[ks], s, 0, 0, 0);
            s = __builtin_amdgcn_mfma_f32_16x16x32_f16(bl, qh[ks], s, 0, 0, 0);
        }
        __builtin_amdgcn_s_setprio(0);

        // row-max: 3 in-lane fmax + 2 shfl (over g4 groups)
        float rmx = fmaxf(fmaxf(s[0], s[1]), fmaxf(s[2], s[3]));
        rmx = fmaxf(rmx, __shfl_xor(rmx, 16));
        rmx = fmaxf(rmx, __shfl_xor(rmx, 32));
        if (g4 == 0) ((float*)(smem + RM_OFF))[kf * 32 + l15 + qf * 16] = rmx;

        LGKM0;
        __builtin_amdgcn_s_barrier();   // B1: RM visible; Kbuf free
        __builtin_amdgcn_sched_barrier(0);

        if (t + 2 < 128) stageK(t + 2, buf);

        // ---- softmax (per-lane q = lane&31, replicated)
        const float* rmf = (const float*)(smem + RM_OFF);
        int ql_ = lane & 31;
        float rm01 = fmaxf(rmf[ql_], rmf[32 + ql_]);
        bool upd = rm01 > mrun + 8.f;        // defer-max (exp2 units, P <= 2^8)
        float sc = upd ? __builtin_amdgcn_exp2f(mrun - rm01) : 1.f;
        if (upd) mrun = rm01;

        float m_q = __shfl(mrun, qloc);
        half4v hp4;
#pragma unroll
        for (int e = 0; e < 4; ++e)
            hp4[e] = (_Float16)__builtin_amdgcn_exp2f(s[e] - m_q);
        *reinterpret_cast<half4v*>(smem + PB_OFF + qloc * 128 + ((kf * 32 + g4 * 8) ^ qsw)) = hp4;

        if (__ballot(sc < 1.f)) {
#pragma unroll
            for (int nf = 0; nf < 2; ++nf) {
                float scn = __shfl(sc, nf * 16 + l15);
#pragma unroll
                for (int m = 0; m < 4; ++m)
#pragma unroll
                    for (int e = 0; e < 4; ++e) { accM[m][nf][e] *= scn; accS[m][nf][e] *= scn; }
            }
        }

        // ---- B2: P visible
        LGKM0;
        __builtin_amdgcn_s_barrier();
        __builtin_amdgcn_sched_barrier(0);

        // ---- V(t) arrival (K(t+2) left in flight)
        if (t <= 125) { VMCNT(8); } else { VMCNT(0); }

        // ---- PV: rowsum(ones) + per-m W-split + MFMA
        half8 pb[2];
#pragma unroll
        for (int nf = 0; nf < 2; ++nf) {
            int q = nf * 16 + l15;
            pb[nf] = *reinterpret_cast<const half8*>(smem + PB_OFF + q * 128 + ((g4 * 16) ^ ((q & 7) << 4)));
        }
        f32x4 po[2];
#pragma unroll
        for (int nf = 0; nf < 2; ++nf) po[nf] = (f32x4){0.f, 0.f, 0.f, 0.f};
        __builtin_amdgcn_s_setprio(1);
#pragma unroll
        for (int nf = 0; nf < 2; ++nf)
            po[nf] = __builtin_amdgcn_mfma_f32_16x16x32_f16(ones8, pb[nf], po[nf], 0, 0, 0);
#pragma unroll
        for (int m = 0; m < 4; ++m) {
            half8 vh8 = vh[m], vl8 = vl[m];
            half8 wh8, wl8;
#pragma unroll
            for (int e = 0; e < 8; ++e) {
                float v = (float)vh8[e] + (float)vl8[e];
                float wv = v * v;
                _Float16 hh = (_Float16)wv;
                wh8[e] = hh; wl8[e] = (_Float16)(wv - (float)hh);
            }
#pragma unroll
            for (int nf = 0; nf < 2; ++nf) {
                accM[m][nf] = __builtin_amdgcn_mfma_f32_16x16x32_f16(vh8, pb[nf], accM[m][nf], 0, 0, 0);
                accM[m][nf] = __builtin_amdgcn_mfma_f32_16x16x32_f16(vl8, pb[nf], accM[m][nf], 0, 0, 0);
                accS[m][nf] = __builtin_amdgcn_mfma_f32_16x16x32_f16(wh8, pb[nf], accS[m][nf], 0, 0, 0);
                accS[m][nf] = __builtin_amdgcn_mfma_f32_16x16x32_f16(wl8, pb[nf], accS[m][nf], 0, 0, 0);
            }
        }
        __builtin_amdgcn_s_setprio(0);

        // lrun update (q = lane&31 -> nf = g4&1)
        float rsum = (g4 & 1) ? po[1][0] : po[0][0];
        lrun = lrun * sc + rsum;
        __builtin_amdgcn_sched_barrier(0);
    }

    // ---- epilogue
    float inv = 1.f / lrun;
    float linv[2];
#pragma unroll
    for (int nf = 0; nf < 2; ++nf) linv[nf] = __shfl(inv, nf * 16 + l15);

#pragma unroll
    for (int m = 0; m < 4; ++m)
#pragma unroll
        for (int nf = 0; nf < 2; ++nf) {
            int qg = q0 + nf * 16 + l15;
#pragma unroll
            for (int e = 0; e < 4; ++e) {
                int ch = w * 64 + m * 16 + g4 * 4 + e;
                float mean = accM[m][nf][e] * linv[nf];
                float sec  = accS[m][nf][e] * linv[nf];
                float var = sec - mean * mean;
                float sd = sqrtf(fmaxf(var, 0.f));
                size_t off = ((size_t)b * CD + ch) * NSP + qg;
                Mout[off] = mean;
                Sout[off] = sd;
            }
        }
}

// ---------------------------------------------------------------- mean-variance-norm + combine
__global__ __launch_bounds__(256) void mvn_kernel(
    const float* __restrict__ content, const float* __restrict__ Mn,
    const float* __restrict__ Sd, float* __restrict__ out)
{
    __shared__ float redS[4], redSS[4];
    const int t = threadIdx.x;
    const size_t base = (size_t)blockIdx.x * NSP;
    const float4* x4 = reinterpret_cast<const float4*>(content + base);
    float s = 0.f, ss = 0.f;
    float4 xv[4];
#pragma unroll
    for (int i = 0; i < 4; ++i) {
        float4 v = x4[i * 256 + t];
        xv[i] = v;
        s  += v.x + v.y + v.z + v.w;
        ss += v.x * v.x + v.y * v.y + v.z * v.z + v.w * v.w;
    }
#pragma unroll
    for (int mk = 1; mk < 64; mk <<= 1) { s += __shfl_xor(s, mk); ss += __shfl_xor(ss, mk); }
    if ((t & 63) == 0) { redS[t >> 6] = s; redSS[t >> 6] = ss; }
    __syncthreads();
    float tot   = redS[0] + redS[1] + redS[2] + redS[3];
    float totss = redSS[0] + redSS[1] + redSS[2] + redSS[3];
    float mu  = tot * (1.f / 4096.f);
    float var = (totss - 4096.f * mu * mu) * (1.f / 4095.f);
    float rstd = 1.f / sqrtf(var + 1e-5f);
    const float4* m4 = reinterpret_cast<const float4*>(Mn + base);
    const float4* s4 = reinterpret_cast<const float4*>(Sd + base);
    float4* o4 = reinterpret_cast<float4*>(out + base);
#pragma unroll
    for (int i = 0; i < 4; ++i) {
        float4 mv = m4[i * 256 + t];
        float4 sv = s4[i * 256 + t];
        float4 v  = xv[i];
        float4 o;
        o.x = sv.x * ((v.x - mu) * rstd) + mv.x;
        o.y = sv.y * ((v.y - mu) * rstd) + mv.y;
        o.z = sv.z * ((v.z - mu) * rstd) + mv.z;
        o.w = sv.w * ((v.w - mu) * rstd) + mv.w;
        o4[i * 256 + t] = o;
    }
}

extern "C" void kernel_launch(void* const* d_in, const int* in_sizes, int n_in,
                              void* d_out, int out_size, void* d_ws, size_t ws_size,
                              hipStream_t stream)
{
    const float* content     = (const float*)d_in[0];
    const float* style       = (const float*)d_in[1];
    const float* content_key = (const float*)d_in[2];
    const float* style_key   = (const float*)d_in[3];
    const float* f_w = (const float*)d_in[4];
    const float* f_b = (const float*)d_in[5];
    const float* g_w = (const float*)d_in[6];
    const float* g_b = (const float*)d_in[7];
    const float* h_w = (const float*)d_in[8];
    const float* h_b = (const float*)d_in[9];
    float* out = (float*)d_out;

    const size_t TS = (size_t)4 * NSP * CD;      // elements per tensor
    _Float16* ws16 = (_Float16*)d_ws;
    _Float16* Qh  = ws16;
    _Float16* Ql  = ws16 + TS;
    _Float16* Kh  = ws16 + 2 * TS;
    _Float16* Kl  = ws16 + 3 * TS;
    _Float16* Vhl = ws16 + 4 * TS;               // 2*TS halves
    float* Mn = (float*)(ws16 + 6 * TS);
    float* Sd = Mn + TS;

    dim3 cgrid(32, 2, 4);
    conv_kernel<0><<<cgrid, 256, 0, stream>>>(f_w, f_b, content_key, Qh, Ql);
    conv_kernel<1><<<cgrid, 256, 0, stream>>>(g_w, g_b, style_key, Kh, Kl);
    conv_kernel<2><<<cgrid, 256, 0, stream>>>(h_w, h_b, style, Vhl, Vhl);
    attn_kernel<<<dim3(512), 256, SMEM_BYTES, stream>>>(Qh, Ql, Kh, Kl, Vhl, Mn, Sd);
    mvn_kernel<<<dim3(1024), 256, 0, stream>>>(content, Mn, Sd, out);
}

// Round 8
// 549.304 us; speedup vs baseline: 3.2524x; 1.0304x over previous
//
#include <hip/hip_runtime.h>
#include <math.h>

#define NSP 4096   // spatial = 64*64
#define CD  256    // channels
#define LOG2E 1.44269504f

typedef _Float16 half8 __attribute__((ext_vector_type(8)));
typedef _Float16 half4v __attribute__((ext_vector_type(4)));
typedef float f32x4 __attribute__((ext_vector_type(4)));
typedef unsigned int u32;

#define VMCNT(n) asm volatile("s_waitcnt vmcnt(" #n ")" ::: "memory")
#define LGKM0    asm volatile("s_waitcnt lgkmcnt(0)" ::: "memory")

__device__ __forceinline__ void gl16(const void* g, void* l) {
    __builtin_amdgcn_global_load_lds((const __attribute__((address_space(1))) u32*)g,
                                     (__attribute__((address_space(3))) u32*)l, 16, 0, 0);
}

// ---------------------------------------------------------------- conv1x1 GEMM
// Y = W(256x256) * X(256x4096) + bias, fp16 hi/lo outputs.
// MODE 0 (Q): [N][C] linear, scaled by LOG2E (softmax in exp2 units).
// MODE 1 (K): LDS-image tiles: tile=n>>5, half-addr = tile*8192 + key*256 + ((g*16 ^ ((key&7)<<4))>>1)
// MODE 2 (V): fragment tiles incl. precomputed W=V^2:
//             slot = (ch>>6)*16 + h*4 + ((ch>>4)&3), h in {vh=0,vl=1,wh=2,wl=3}
//             half-addr = tile*32768 + slot*512 + (kin>>3)*128 + (ch&15)*8 + (kin&7)
template<int MODE>
__global__ __launch_bounds__(256, 2) void conv_kernel(
    const float* __restrict__ W, const float* __restrict__ bias,
    const float* __restrict__ Xall, _Float16* __restrict__ Yh, _Float16* __restrict__ Yl)
{
    const int b = blockIdx.z;
    const float* X = Xall + (size_t)b * CD * NSP;
    _Float16* Yhb = Yh + (size_t)b * CD * NSP * (MODE == 2 ? 4 : 1);
    _Float16* Ylb = (MODE == 2) ? nullptr : Yl + (size_t)b * CD * NSP;
    __shared__ float Ws[16][128];
    __shared__ float Xs[16][128];
    const int t = threadIdx.x;
    const int tx = t & 15, ty = t >> 4;
    const int m0 = blockIdx.y * 128, n0 = blockIdx.x * 128;
    float acc[8][8];
#pragma unroll
    for (int i = 0; i < 8; ++i)
#pragma unroll
        for (int j = 0; j < 8; ++j) acc[i][j] = 0.f;

    for (int k0 = 0; k0 < CD; k0 += 16) {
        __syncthreads();
        {
            int m = t >> 1, k = (t & 1) * 8;
            float4 w0 = *reinterpret_cast<const float4*>(&W[(size_t)(m0 + m) * CD + k0 + k]);
            float4 w1 = *reinterpret_cast<const float4*>(&W[(size_t)(m0 + m) * CD + k0 + k + 4]);
            Ws[k + 0][m] = w0.x; Ws[k + 1][m] = w0.y; Ws[k + 2][m] = w0.z; Ws[k + 3][m] = w0.w;
            Ws[k + 4][m] = w1.x; Ws[k + 5][m] = w1.y; Ws[k + 6][m] = w1.z; Ws[k + 7][m] = w1.w;
        }
        {
            int k = t >> 4, n = (t & 15) * 8;
            *reinterpret_cast<float4*>(&Xs[k][n]) =
                *reinterpret_cast<const float4*>(&X[(size_t)(k0 + k) * NSP + n0 + n]);
            *reinterpret_cast<float4*>(&Xs[k][n + 4]) =
                *reinterpret_cast<const float4*>(&X[(size_t)(k0 + k) * NSP + n0 + n + 4]);
        }
        __syncthreads();
#pragma unroll
        for (int k = 0; k < 16; ++k) {
            float a[8], bb[8];
            float4 a0 = *reinterpret_cast<const float4*>(&Ws[k][ty * 8]);
            float4 a1 = *reinterpret_cast<const float4*>(&Ws[k][ty * 8 + 4]);
            float4 b0 = *reinterpret_cast<const float4*>(&Xs[k][tx * 4]);
            float4 b1 = *reinterpret_cast<const float4*>(&Xs[k][64 + tx * 4]);
            a[0]=a0.x; a[1]=a0.y; a[2]=a0.z; a[3]=a0.w;
            a[4]=a1.x; a[5]=a1.y; a[6]=a1.z; a[7]=a1.w;
            bb[0]=b0.x; bb[1]=b0.y; bb[2]=b0.z; bb[3]=b0.w;
            bb[4]=b1.x; bb[5]=b1.y; bb[6]=b1.z; bb[7]=b1.w;
#pragma unroll
            for (int i = 0; i < 8; ++i)
#pragma unroll
                for (int j = 0; j < 8; ++j) acc[i][j] = fmaf(a[i], bb[j], acc[i][j]);
        }
    }
    float bv[8];
#pragma unroll
    for (int i = 0; i < 8; ++i) bv[i] = bias[m0 + ty * 8 + i];

    if (MODE == 0) {
#pragma unroll
        for (int jj = 0; jj < 8; ++jj) {
            int n = n0 + ((jj < 4) ? (tx * 4 + jj) : (64 + tx * 4 + (jj - 4)));
            half4v h0, h1, l0, l1;
#pragma unroll
            for (int i = 0; i < 4; ++i) {
                float y0 = (acc[i][jj] + bv[i]) * LOG2E;
                _Float16 hh0 = (_Float16)y0; h0[i] = hh0; l0[i] = (_Float16)(y0 - (float)hh0);
                float y1 = (acc[i + 4][jj] + bv[i + 4]) * LOG2E;
                _Float16 hh1 = (_Float16)y1; h1[i] = hh1; l1[i] = (_Float16)(y1 - (float)hh1);
            }
            size_t off = (size_t)n * CD + m0 + ty * 8;
            *reinterpret_cast<half4v*>(&Yhb[off])     = h0;
            *reinterpret_cast<half4v*>(&Yhb[off + 4]) = h1;
            *reinterpret_cast<half4v*>(&Ylb[off])     = l0;
            *reinterpret_cast<half4v*>(&Ylb[off + 4]) = l1;
        }
    } else if (MODE == 1) {
#pragma unroll
        for (int jj = 0; jj < 8; ++jj) {
            int n = n0 + ((jj < 4) ? (tx * 4 + jj) : (64 + tx * 4 + (jj - 4)));
            int tile = n >> 5, key = n & 31;
            int g = (m0 + ty * 8) >> 3;
            size_t base = (size_t)tile * 8192 + (size_t)key * 256
                        + ((((g * 16)) ^ ((key & 7) << 4)) >> 1);
            half4v h0, h1, l0, l1;
#pragma unroll
            for (int i = 0; i < 4; ++i) {
                float y0 = acc[i][jj] + bv[i];
                _Float16 hh0 = (_Float16)y0; h0[i] = hh0; l0[i] = (_Float16)(y0 - (float)hh0);
                float y1 = acc[i + 4][jj] + bv[i + 4];
                _Float16 hh1 = (_Float16)y1; h1[i] = hh1; l1[i] = (_Float16)(y1 - (float)hh1);
            }
            *reinterpret_cast<half4v*>(&Yhb[base])     = h0;
            *reinterpret_cast<half4v*>(&Yhb[base + 4]) = h1;
            *reinterpret_cast<half4v*>(&Ylb[base])     = l0;
            *reinterpret_cast<half4v*>(&Ylb[base + 4]) = l1;
        }
    } else {
        // V fragments + precomputed W=V^2, each hi/lo
#pragma unroll
        for (int i = 0; i < 8; ++i) {
            int ch = m0 + ty * 8 + i;
            int wv_ = ch >> 6, mv = (ch >> 4) & 3, lv = ch & 15;
            size_t chbase = (size_t)(wv_ * 16 + mv) * 512 + lv * 8;
#pragma unroll
            for (int grp = 0; grp < 2; ++grp) {
                int n = n0 + grp * 64 + tx * 4;
                int tile = n >> 5, kin = n & 31;
                int g4v = kin >> 3, pos0 = kin & 7;
                half4v hv, lv4, whv, wlv;
#pragma unroll
                for (int j = 0; j < 4; ++j) {
                    float y = acc[i][grp * 4 + j] + bv[i];
                    _Float16 hh = (_Float16)y; hv[j] = hh; lv4[j] = (_Float16)(y - (float)hh);
                    float wy = y * y;
                    _Float16 wh_ = (_Float16)wy; whv[j] = wh_; wlv[j] = (_Float16)(wy - (float)wh_);
                }
                size_t tb = (size_t)tile * 32768 + chbase + (size_t)g4v * 128 + pos0;
                *reinterpret_cast<half4v*>(&Yhb[tb])        = hv;
                *reinterpret_cast<half4v*>(&Yhb[tb + 2048]) = lv4;
                *reinterpret_cast<half4v*>(&Yhb[tb + 4096]) = whv;
                *reinterpret_cast<half4v*>(&Yhb[tb + 6144]) = wlv;
            }
        }
    }
}

// ---------------------------------------------------------------- fused MFMA flash attention
// 32 q-rows/block, 256 threads (4 waves), 128 key-tiles of 32, 512 blocks (2/CU).
// Swapped QK^T (A=K, B=Q), 3 independent S accumulator chains.
// V/W direct global->reg (wave-private, conv-precomputed W); PV = pure MFMA.
// LDS: KB 0 (K dbuf hi/lo 64K) | PB 65536 (P[32][128B] 4K) | RM 69632 (2x32 f32)
#define KB_OFF 0
#define PB_OFF 65536
#define RM_OFF 69632
#define SMEM_BYTES 69888

__global__ __launch_bounds__(256, 2) void attn_kernel(
    const _Float16* __restrict__ Qh_g, const _Float16* __restrict__ Ql_g,
    const _Float16* __restrict__ Kh_g, const _Float16* __restrict__ Kl_g,
    const _Float16* __restrict__ Vq_g,
    _Float16* __restrict__ Mout, _Float16* __restrict__ Sout)
{
    extern __shared__ char smem[];
    const int tid = threadIdx.x;
    const int lane = tid & 63;
    const int w = tid >> 6;          // 0..3
    const int g4 = lane >> 4;        // 0..3
    const int l15 = lane & 15;
    const int kf = w & 1;            // key-frag (16 keys)
    const int qf = w >> 1;           // q-frag (16 q)

    // XCD-aware decode: 512 blocks, bid&7 = XCD, 2 XCDs per batch, bijective.
    const int bid = blockIdx.x;
    const int b = (bid & 7) >> 1;
    const int qb = ((bid >> 3) << 1) | (bid & 1);   // 0..127
    const int q0 = qb * 32;

    const size_t bNC = (size_t)b * NSP * CD;
    const _Float16* Qhb = Qh_g + bNC;
    const _Float16* Qlb = Ql_g + bNC;
    const _Float16* Khb = Kh_g + bNC;
    const _Float16* Klb = Kl_g + bNC;
    const _Float16* Vb  = Vq_g + bNC * 4;   // 4 halves per element (vh,vl,wh,wl)

    // Q fragments (B-operand) in registers
    const int qrow = q0 + qf * 16 + l15;
    half8 qh[8], ql[8];
#pragma unroll
    for (int ks = 0; ks < 8; ++ks) {
        qh[ks] = *reinterpret_cast<const half8*>(Qhb + (size_t)qrow * CD + ks * 32 + g4 * 8);
        ql[ks] = *reinterpret_cast<const half8*>(Qlb + (size_t)qrow * CD + ks * 32 + g4 * 8);
    }

    auto stageK = [&](int t, int buf) {
        const _Float16* sh = Khb + (size_t)t * 8192 + tid * 8;
        const _Float16* sl = Klb + (size_t)t * 8192 + tid * 8;
        char* d = smem + KB_OFF + buf * 32768 + tid * 16;
#pragma unroll
        for (int j = 0; j < 4; ++j) {
            gl16(sh + j * 2048, d + j * 4096);
            gl16(sl + j * 2048, d + 16384 + j * 4096);
        }
    };

    stageK(0, 0); stageK(1, 1);

    f32x4 accM[4][2], accS[4][2];
#pragma unroll
    for (int m = 0; m < 4; ++m)
#pragma unroll
        for (int nf = 0; nf < 2; ++nf) {
            accM[m][nf] = (f32x4){0.f, 0.f, 0.f, 0.f};
            accS[m][nf] = (f32x4){0.f, 0.f, 0.f, 0.f};
        }
    float mrun = -3.0e38f, lrun = 0.f;

    half8 ones8;
#pragma unroll
    for (int e = 0; e < 8; ++e) ones8[e] = (_Float16)1.f;

    const int key = kf * 16 + l15;
    const int ksw = (key & 7) << 4;
    const int qloc = qf * 16 + l15;                    // this wave's q for S/P
    const int qsw = (qloc & 7) << 4;
    const size_t vlane = (size_t)g4 * 128 + (size_t)l15 * 8;

    half8 vh[4], vl[4], wh[4], wl[4];

    for (int t = 0; t < 128; ++t) {
        const int buf = t & 1;

        // ---- B0: K(t) arrived
        if (t <= 126) { VMCNT(8); } else { VMCNT(0); }
        LGKM0;
        __builtin_amdgcn_s_barrier();
        __builtin_amdgcn_sched_barrier(0);

        // ---- S-phase: s = K x Q, 3 independent accumulator chains
        const char* krow = smem + KB_OFF + buf * 32768 + key * 512;
        f32x4 sA = (f32x4){0.f, 0.f, 0.f, 0.f};
        f32x4 sB = sA, sC = sA;
        __builtin_amdgcn_s_setprio(1);
#pragma unroll
        for (int ks = 0; ks < 8; ++ks) {
            int off = ((ks * 4 + g4) * 16) ^ ksw;
            half8 bh = *reinterpret_cast<const half8*>(krow + off);
            half8 bl = *reinterpret_cast<const half8*>(krow + 16384 + off);
            sA = __builtin_amdgcn_mfma_f32_16x16x32_f16(bh, qh[ks], sA, 0, 0, 0);
            sB = __builtin_amdgcn_mfma_f32_16x16x32_f16(bh, ql[ks], sB, 0, 0, 0);
            sC = __builtin_amdgcn_mfma_f32_16x16x32_f16(bl, qh[ks], sC, 0, 0, 0);
        }
        __builtin_amdgcn_s_setprio(0);
        f32x4 s = (sA + sB) + sC;

        // row-max: 3 in-lane fmax + 2 shfl (over g4 groups)
        float rmx = fmaxf(fmaxf(s[0], s[1]), fmaxf(s[2], s[3]));
        rmx = fmaxf(rmx, __shfl_xor(rmx, 16));
        rmx = fmaxf(rmx, __shfl_xor(rmx, 32));
        if (g4 == 0) ((float*)(smem + RM_OFF))[kf * 32 + l15 + qf * 16] = rmx;

        LGKM0;
        __builtin_amdgcn_s_barrier();   // B1: RM visible; Kbuf free
        __builtin_amdgcn_sched_barrier(0);

        // issue V/W register loads (wave-private), then next K stage
        {
            const _Float16* Vt = Vb + (size_t)t * 32768;
#pragma unroll
            for (int m = 0; m < 4; ++m) {
                vh[m] = *reinterpret_cast<const half8*>(Vt + (size_t)(w * 16 + m) * 512 + vlane);
                vl[m] = *reinterpret_cast<const half8*>(Vt + (size_t)(w * 16 + 4 + m) * 512 + vlane);
                wh[m] = *reinterpret_cast<const half8*>(Vt + (size_t)(w * 16 + 8 + m) * 512 + vlane);
                wl[m] = *reinterpret_cast<const half8*>(Vt + (size_t)(w * 16 + 12 + m) * 512 + vlane);
            }
        }
        if (t + 2 < 128) stageK(t + 2, buf);

        // ---- softmax (per-lane q = lane&31, replicated)
        const float* rmf = (const float*)(smem + RM_OFF);
        int ql_ = lane & 31;
        float rm01 = fmaxf(rmf[ql_], rmf[32 + ql_]);
        bool upd = rm01 > mrun + 8.f;        // defer-max (exp2 units, P <= 2^8)
        float sc = upd ? __builtin_amdgcn_exp2f(mrun - rm01) : 1.f;
        if (upd) mrun = rm01;

        float m_q = __shfl(mrun, qloc);
        half4v hp4;
#pragma unroll
        for (int e = 0; e < 4; ++e)
            hp4[e] = (_Float16)__builtin_amdgcn_exp2f(s[e] - m_q);
        *reinterpret_cast<half4v*>(smem + PB_OFF + qloc * 128 + ((kf * 32 + g4 * 8) ^ qsw)) = hp4;

        if (__ballot(sc < 1.f)) {
#pragma unroll
            for (int nf = 0; nf < 2; ++nf) {
                float scn = __shfl(sc, nf * 16 + l15);
#pragma unroll
                for (int m = 0; m < 4; ++m)
#pragma unroll
                    for (int e = 0; e < 4; ++e) { accM[m][nf][e] *= scn; accS[m][nf][e] *= scn; }
            }
        }

        // ---- B2: P visible
        LGKM0;
        __builtin_amdgcn_s_barrier();
        __builtin_amdgcn_sched_barrier(0);

        // ---- V/W arrival (K(t+2) left in flight)
        if (t <= 125) { VMCNT(8); } else { VMCNT(0); }

        // ---- PV: rowsum(ones) + pure-MFMA passes (vh, vl, wh, wl), 8 indep chains each
        half8 pb[2];
#pragma unroll
        for (int nf = 0; nf < 2; ++nf) {
            int q = nf * 16 + l15;
            pb[nf] = *reinterpret_cast<const half8*>(smem + PB_OFF + q * 128 + ((g4 * 16) ^ ((q & 7) << 4)));
        }
        f32x4 po[2];
#pragma unroll
        for (int nf = 0; nf < 2; ++nf) po[nf] = (f32x4){0.f, 0.f, 0.f, 0.f};
        __builtin_amdgcn_s_setprio(1);
#pragma unroll
        for (int nf = 0; nf < 2; ++nf)
            po[nf] = __builtin_amdgcn_mfma_f32_16x16x32_f16(ones8, pb[nf], po[nf], 0, 0, 0);
#pragma unroll
        for (int m = 0; m < 4; ++m)
#pragma unroll
            for (int nf = 0; nf < 2; ++nf)
                accM[m][nf] = __builtin_amdgcn_mfma_f32_16x16x32_f16(vh[m], pb[nf], accM[m][nf], 0, 0, 0);
#pragma unroll
        for (int m = 0; m < 4; ++m)
#pragma unroll
            for (int nf = 0; nf < 2; ++nf)
                accM[m][nf] = __builtin_amdgcn_mfma_f32_16x16x32_f16(vl[m], pb[nf], accM[m][nf], 0, 0, 0);
#pragma unroll
        for (int m = 0; m < 4; ++m)
#pragma unroll
            for (int nf = 0; nf < 2; ++nf)
                accS[m][nf] = __builtin_amdgcn_mfma_f32_16x16x32_f16(wh[m], pb[nf], accS[m][nf], 0, 0, 0);
#pragma unroll
        for (int m = 0; m < 4; ++m)
#pragma unroll
            for (int nf = 0; nf < 2; ++nf)
                accS[m][nf] = __builtin_amdgcn_mfma_f32_16x16x32_f16(wl[m], pb[nf], accS[m][nf], 0, 0, 0);
        __builtin_amdgcn_s_setprio(0);

        // lrun update (q = lane&31 -> nf = g4&1)
        float rsum = (g4 & 1) ? po[1][0] : po[0][0];
        lrun = lrun * sc + rsum;
        __builtin_amdgcn_sched_barrier(0);
    }

    // ---- epilogue (fp16 Mean/Std, [B][C][N])
    float inv = 1.f / lrun;
    float linv[2];
#pragma unroll
    for (int nf = 0; nf < 2; ++nf) linv[nf] = __shfl(inv, nf * 16 + l15);

#pragma unroll
    for (int m = 0; m < 4; ++m)
#pragma unroll
        for (int nf = 0; nf < 2; ++nf) {
            int qg = q0 + nf * 16 + l15;
#pragma unroll
            for (int e = 0; e < 4; ++e) {
                int ch = w * 64 + m * 16 + g4 * 4 + e;
                float mean = accM[m][nf][e] * linv[nf];
                float sec  = accS[m][nf][e] * linv[nf];
                float var = sec - mean * mean;
                float sd = sqrtf(fmaxf(var, 0.f));
                size_t off = ((size_t)b * CD + ch) * NSP + qg;
                Mout[off] = (_Float16)mean;
                Sout[off] = (_Float16)sd;
            }
        }
}

// ---------------------------------------------------------------- mean-variance-norm + combine
__global__ __launch_bounds__(256) void mvn_kernel(
    const float* __restrict__ content, const _Float16* __restrict__ Mn,
    const _Float16* __restrict__ Sd, float* __restrict__ out)
{
    __shared__ float redS[4], redSS[4];
    const int t = threadIdx.x;
    const size_t base = (size_t)blockIdx.x * NSP;
    const float4* x4 = reinterpret_cast<const float4*>(content + base);
    float s = 0.f, ss = 0.f;
    float4 xv[4];
#pragma unroll
    for (int i = 0; i < 4; ++i) {
        float4 v = x4[i * 256 + t];
        xv[i] = v;
        s  += v.x + v.y + v.z + v.w;
        ss += v.x * v.x + v.y * v.y + v.z * v.z + v.w * v.w;
    }
#pragma unroll
    for (int mk = 1; mk < 64; mk <<= 1) { s += __shfl_xor(s, mk); ss += __shfl_xor(ss, mk); }
    if ((t & 63) == 0) { redS[t >> 6] = s; redSS[t >> 6] = ss; }
    __syncthreads();
    float tot   = redS[0] + redS[1] + redS[2] + redS[3];
    float totss = redSS[0] + redSS[1] + redSS[2] + redSS[3];
    float mu  = tot * (1.f / 4096.f);
    float var = (totss - 4096.f * mu * mu) * (1.f / 4095.f);
    float rstd = 1.f / sqrtf(var + 1e-5f);
    const half4v* m4 = reinterpret_cast<const half4v*>(Mn + base);
    const half4v* s4 = reinterpret_cast<const half4v*>(Sd + base);
    float4* o4 = reinterpret_cast<float4*>(out + base);
#pragma unroll
    for (int i = 0; i < 4; ++i) {
        half4v mv = m4[i * 256 + t];
        half4v sv = s4[i * 256 + t];
        float4 v  = xv[i];
        float4 o;
        o.x = (float)sv[0] * ((v.x - mu) * rstd) + (float)mv[0];
        o.y = (float)sv[1] * ((v.y - mu) * rstd) + (float)mv[1];
        o.z = (float)sv[2] * ((v.z - mu) * rstd) + (float)mv[2];
        o.w = (float)sv[3] * ((v.w - mu) * rstd) + (float)mv[3];
        o4[i * 256 + t] = o;
    }
}

extern "C" void kernel_launch(void* const* d_in, const int* in_sizes, int n_in,
                              void* d_out, int out_size, void* d_ws, size_t ws_size,
                              hipStream_t stream)
{
    const float* content     = (const float*)d_in[0];
    const float* style       = (const float*)d_in[1];
    const float* content_key = (const float*)d_in[2];
    const float* style_key   = (const float*)d_in[3];
    const float* f_w = (const float*)d_in[4];
    const float* f_b = (const float*)d_in[5];
    const float* g_w = (const float*)d_in[6];
    const float* g_b = (const float*)d_in[7];
    const float* h_w = (const float*)d_in[8];
    const float* h_b = (const float*)d_in[9];
    float* out = (float*)d_out;

    const size_t TS = (size_t)4 * NSP * CD;      // elements per tensor
    _Float16* ws16 = (_Float16*)d_ws;
    _Float16* Qh = ws16;                 // TS
    _Float16* Ql = ws16 + TS;
    _Float16* Kh = ws16 + 2 * TS;
    _Float16* Kl = ws16 + 3 * TS;
    _Float16* Vq = ws16 + 4 * TS;        // 4*TS (vh,vl,wh,wl fragments)
    _Float16* Mn = ws16 + 8 * TS;        // TS fp16
    _Float16* Sd = ws16 + 9 * TS;        // TS fp16 -> total 10*TS halves = 83.9 MB

    dim3 cgrid(32, 2, 4);
    conv_kernel<0><<<cgrid, 256, 0, stream>>>(f_w, f_b, content_key, Qh, Ql);
    conv_kernel<1><<<cgrid, 256, 0, stream>>>(g_w, g_b, style_key, Kh, Kl);
    conv_kernel<2><<<cgrid, 256, 0, stream>>>(h_w, h_b, style, Vq, Vq);
    attn_kernel<<<dim3(512), 256, SMEM_BYTES, stream>>>(Qh, Ql, Kh, Kl, Vq, Mn, Sd);
    mvn_kernel<<<dim3(1024), 256, 0, stream>>>(content, Mn, Sd, out);
}